// Round 4
// baseline (195.895 us; speedup 1.0000x reference)
//
#include <hip/hip_runtime.h>
#include <math.h>
#include <stdint.h>

// ---------------------------------------------------------------------------
// Algebraic reductions (verified, absmax 2.4e-4):
//  * 2-step loop idempotent -> run once; node branch cancels entirely.
//  * Composed GEMM: g = x_edge @ Wc + bc, Wc = et_w @ egru_wih^T [512,384].
//  * GRU gates + softmax-pool fused into GEMM epilogue (block = (b,i) group).
//  * Heads: layer1 (bf16-split MFMA) + ReLU + layer2 fused in one kernel.
//  * Precision: split-bf16 (hi+lo) 3-term MFMA ~= f32 accuracy.
// Round-4 change: 1-deep prefetch double-buffered K-loop (stage kt+1 while
// computing kt, ONE barrier per kt) -> mega becomes HBM-bound (~21 us floor).
// ---------------------------------------------------------------------------

typedef __attribute__((ext_vector_type(8))) short short8;
typedef __attribute__((ext_vector_type(4))) float f32x4;

#define DEVINL __device__ __forceinline__

DEVINL float sigmoidf_(float x) { return 1.0f / (1.0f + __expf(-x)); }
DEVINL float tanhf_(float x) {
    float e = __expf(2.0f * x);
    return (e - 1.0f) / (e + 1.0f);
}
DEVINL short bf16_rne(float f) {
    uint32_t u = __float_as_uint(f);
    u += 0x7FFFu + ((u >> 16) & 1u);
    return (short)(u >> 16);
}
DEVINL float bf16_to_f(short s) {
    return __uint_as_float(((uint32_t)(uint16_t)s) << 16);
}
DEVINL void gload_lds16(const void* g, void* l) {
    __builtin_amdgcn_global_load_lds(
        (const __attribute__((address_space(1))) void*)(uintptr_t)g,
        (__attribute__((address_space(3))) void*)(uint32_t)(uintptr_t)l,
        16, 0, 0);
}

// ---------------- prep: Wc in MFMA fragment order, split hi/lo -------------
// Wc[k][n] = sum_m et_w[k][m] * egru_wih[n][m];  k<512, n<384.
// Fragment order: [kt(16)][ct(24)][lane(64)][j(8)],
//   k = kt*32 + ((lane>>4)&3)*8 + j,  n = ct*16 + (lane&15).
__global__ __launch_bounds__(256) void prep_w(
    const float* __restrict__ et_w, const float* __restrict__ wih,
    short* __restrict__ Wf_hi, short* __restrict__ Wf_lo)
{
    int idx = blockIdx.x * 256 + threadIdx.x;   // idx = n*512 + k
    int n = idx >> 9, k = idx & 511;
    const float4* a = (const float4*)(et_w + (size_t)k * 128);
    const float4* b = (const float4*)(wih + (size_t)n * 128);
    float acc = 0.f;
#pragma unroll 8
    for (int m = 0; m < 32; ++m) {
        float4 x = a[m], y = b[m];
        acc += x.x * y.x + x.y * y.y + x.z * y.z + x.w * y.w;
    }
    short h = bf16_rne(acc);
    short l = bf16_rne(acc - bf16_to_f(h));
    int kt = k >> 5, ct = n >> 4;
    int lane = (((k >> 3) & 3) << 4) | (n & 15);
    int j = k & 7;
    size_t fidx = ((((size_t)kt * 24 + ct) * 64) + lane) * 8 + j;
    Wf_hi[fidx] = h;
    Wf_lo[fidx] = l;
}

// bc[n] = et_b . egru_wih[n] + egru_bih[n] (+ egru_bhh[n] for n<256)
__global__ __launch_bounds__(256) void prep_b(
    const float* __restrict__ et_b, const float* __restrict__ wih,
    const float* __restrict__ bih, const float* __restrict__ bhh,
    float* __restrict__ bc)
{
    int n = blockIdx.x * 256 + threadIdx.x;
    if (n >= 384) return;
    float acc = bih[n] + (n < 256 ? bhh[n] : 0.f);
    const float* w = wih + (size_t)n * 128;
    for (int m = 0; m < 128; ++m) acc = fmaf(et_b[m], w[m], acc);
    bc[n] = acc;
}

// ---------------- prep: heads W1 (3x [256,512]) in fragment order ----------
// Fragment order: [h(3)][kt(8)][ct(32)][lane(64)][j(8)],
//   k = kt*32 + ((lane>>4)&3)*8 + j,  c = ct*16 + (lane&15).
__global__ __launch_bounds__(256) void prep_w1(
    const float* __restrict__ w1a, const float* __restrict__ w1b,
    const float* __restrict__ w1c,
    short* __restrict__ Wf1_hi, short* __restrict__ Wf1_lo)
{
    int idx = blockIdx.x * 256 + threadIdx.x;   // < 3*131072
    int h = idx >> 17;
    int r = idx & 131071;
    int k = r >> 9;
    int c = r & 511;
    const float* w1 = (h == 0) ? w1a : (h == 1) ? w1b : w1c;
    float v = w1[(size_t)k * 512 + c];
    short hi = bf16_rne(v);
    short lo = bf16_rne(v - bf16_to_f(hi));
    int kt = k >> 5, ct = c >> 4;
    int lane = (((k >> 3) & 3) << 4) | (c & 15);
    int j = k & 7;
    size_t fidx = ((((size_t)h * 8 + kt) * 32 + ct) * 64 + lane) * 8 + j;
    Wf1_hi[fidx] = hi;
    Wf1_lo[fidx] = lo;
}

// ---------------- mega: dbuf-pipelined GEMM + GRU gates + softmax-pool -----
// One block per (b,i) group: 64 rows x 384 cols, K=512 (16 kt of 32).
// LDS: B dbuf 2*48KB + A dbuf 2*8KB = 112 KB -> 1 block/CU.
__global__ __launch_bounds__(256, 1) void mega_kernel(
    const float* __restrict__ x_edge,
    const short* __restrict__ Wf_hi, const short* __restrict__ Wf_lo,
    const float* __restrict__ bc, const float* __restrict__ bhh,
    const float* __restrict__ natt_w, const float* __restrict__ eatt_w,
    float* __restrict__ nh_p, float* __restrict__ u_out)
{
    __shared__ __align__(16) char smem[114688];
    // buf b: B_hi at b*49152 (24576 B), B_lo at b*49152+24576
    //        A_hi at 98304+b*8192 (4096 B), A_lo at +4096
    const int t = threadIdx.x;
    const int wv = t >> 6, lane = t & 63;
    const int g = blockIdx.x;
    const size_t bm = (size_t)g * 64;

    const int arow = t >> 2, akb = t & 3;
    const int abyte = ((((arow >> 4) * 64) + ((akb << 4) | (arow & 15))) * 8) * 2;
    const float* aptr = x_edge + (bm + arow) * 512 + akb * 8;

    f32x4 acc[4][6] = {};

    // ---- prologue: A(0) regs + B(0) stage -> buf0 ----
    float4 a0 = *(const float4*)(aptr);
    float4 a1 = *(const float4*)(aptr + 4);
    {
        const char* sh = (const char*)(Wf_hi);
        const char* sl = (const char*)(Wf_lo);
#pragma unroll
        for (int i = 0; i < 6; ++i) {
            int ch = i * 4 + wv;
            int off = ch * 1024 + lane * 16;
            gload_lds16(sh + off, smem + ch * 1024);
            gload_lds16(sl + off, smem + 24576 + ch * 1024);
        }
    }
    {
        float av[8] = {a0.x, a0.y, a0.z, a0.w, a1.x, a1.y, a1.z, a1.w};
        short8 h8, l8;
#pragma unroll
        for (int j = 0; j < 8; ++j) {
            short h = bf16_rne(av[j]);
            h8[j] = h;
            l8[j] = bf16_rne(av[j] - bf16_to_f(h));
        }
        *(short8*)(smem + 98304 + abyte) = h8;
        *(short8*)(smem + 98304 + 4096 + abyte) = l8;
    }
    __syncthreads();

    // ---- main loop: stage(kt+1) || compute(kt), ONE barrier per kt ----
    for (int kt = 0; kt < 16; ++kt) {
        const int cur = kt & 1;
        const char* Bh_c = smem + cur * 49152;
        const char* Bl_c = Bh_c + 24576;
        const char* Ah_c = smem + 98304 + cur * 8192;
        const char* Al_c = Ah_c + 4096;

        float4 b0, b1;
        if (kt < 15) {
            const char* sh = (const char*)(Wf_hi + (size_t)(kt + 1) * 12288);
            const char* sl = (const char*)(Wf_lo + (size_t)(kt + 1) * 12288);
            char* dBh = smem + (cur ^ 1) * 49152;
#pragma unroll
            for (int i = 0; i < 6; ++i) {
                int ch = i * 4 + wv;
                int off = ch * 1024 + lane * 16;
                gload_lds16(sh + off, dBh + ch * 1024);
                gload_lds16(sl + off, dBh + 24576 + ch * 1024);
            }
            b0 = *(const float4*)(aptr + (size_t)(kt + 1) * 32);
            b1 = *(const float4*)(aptr + (size_t)(kt + 1) * 32 + 4);
        }

        short8 Ah[4], Al[4];
#pragma unroll
        for (int rt = 0; rt < 4; ++rt) {
            Ah[rt] = *(const short8*)(Ah_c + (rt * 64 + lane) * 16);
            Al[rt] = *(const short8*)(Al_c + (rt * 64 + lane) * 16);
        }
#pragma unroll
        for (int c = 0; c < 6; ++c) {
            int ctg = ((c >> 1) << 3) + (wv << 1) + (c & 1);
            short8 Bh = *(const short8*)(Bh_c + (ctg * 64 + lane) * 16);
            short8 Bl = *(const short8*)(Bl_c + (ctg * 64 + lane) * 16);
#pragma unroll
            for (int rt = 0; rt < 4; ++rt) {
                acc[rt][c] = __builtin_amdgcn_mfma_f32_16x16x32_bf16(Ah[rt], Bh, acc[rt][c], 0, 0, 0);
                acc[rt][c] = __builtin_amdgcn_mfma_f32_16x16x32_bf16(Al[rt], Bh, acc[rt][c], 0, 0, 0);
                acc[rt][c] = __builtin_amdgcn_mfma_f32_16x16x32_bf16(Ah[rt], Bl, acc[rt][c], 0, 0, 0);
            }
        }

        if (kt < 15) {
            float av[8] = {b0.x, b0.y, b0.z, b0.w, b1.x, b1.y, b1.z, b1.w};
            short8 h8, l8;
#pragma unroll
            for (int j = 0; j < 8; ++j) {
                short h = bf16_rne(av[j]);
                h8[j] = h;
                l8[j] = bf16_rne(av[j] - bf16_to_f(h));
            }
            char* dAh = smem + 98304 + (cur ^ 1) * 8192;
            *(short8*)(dAh + abyte) = h8;
            *(short8*)(dAh + 4096 + abyte) = l8;
        }
        __syncthreads();
    }

    // ---- epilogue: GRU gates -> eh_s (overlay LDS) ----
    const int EHP = 132;
    float* eh_s = (float*)smem;                 // [64][132] f32
#pragma unroll
    for (int cc = 0; cc < 2; ++cc) {
        int o = (wv << 5) + (cc << 4) + (lane & 15);
        float bco = bc[o], bcz = bc[128 + o], bcn = bc[256 + o], bn3 = bhh[256 + o];
#pragma unroll
        for (int rt = 0; rt < 4; ++rt) {
#pragma unroll
            for (int q = 0; q < 4; ++q) {
                int row = rt * 16 + ((lane >> 4) << 2) + q;
                float r = sigmoidf_(acc[rt][cc][q] + bco);
                float z = sigmoidf_(acc[rt][2 + cc][q] + bcz);
                float n = tanhf_(acc[rt][4 + cc][q] + bcn + r * bn3);
                eh_s[row * EHP + o] = (1.0f - z) * n;
            }
        }
    }
    __syncthreads();

    // ---- softmax-pool over j (64 rows) ----
    float* red = eh_s + 64 * EHP;
    float* s2v = red + 256;
    float* ewv = s2v + 64;
    {
        int j = t >> 2, q = t & 3;
        const float* row = eh_s + j * EHP + q * 32;
        const float* wb = natt_w + 128 + q * 32;
        float a = 0.f;
#pragma unroll
        for (int k2 = 0; k2 < 32; ++k2) a = fmaf(row[k2], wb[k2], a);
        red[t] = a;
    }
    __syncthreads();
    if (t < 64) s2v[t] = red[4 * t] + red[4 * t + 1] + red[4 * t + 2] + red[4 * t + 3];
    __syncthreads();
    if (t < 64) {
        float m = -1e30f;
        for (int j = 0; j < 64; ++j) m = fmaxf(m, s2v[j]);
        ewv[t] = __expf(s2v[t] - m);
    }
    __syncthreads();
    float inv = 0.f;
    for (int j = 0; j < 64; ++j) inv += ewv[j];
    inv = 1.0f / inv;
    {
        int o = t & 127, h = t >> 7;
        float a = 0.f;
        for (int j = h * 32; j < h * 32 + 32; ++j)
            a = fmaf(ewv[j], eh_s[j * EHP + o], a);
        __syncthreads();
        red[t] = a;
    }
    __syncthreads();
    if (t < 128) {
        float v = (red[t] + red[t + 128]) * inv;
        nh_p[(size_t)g * 128 + t] = v;
        red[t] = v * eatt_w[t];
    }
    __syncthreads();
    for (int s = 64; s > 0; s >>= 1) {
        if (t < s) red[t] += red[t + s];
        __syncthreads();
    }
    if (t == 0) u_out[g] = red[0];
}

// -------- classifier input --------------------------------------------------
__global__ __launch_bounds__(128) void ci_kernel(
    const float* __restrict__ nh_p, const float* __restrict__ u,
    const int* __restrict__ pairs, float* __restrict__ ci)
{
    const int bp = blockIdx.x;
    const int b  = bp >> 7;
    const int t  = threadIdx.x;
    int i0 = pairs[bp * 2 + 0];
    int i1 = pairs[bp * 2 + 1];
    const float* n0 = nh_p + (size_t)(b * 64 + i0) * 128;
    const float* n1 = nh_p + (size_t)(b * 64 + i1) * 128;
    float s = sigmoidf_(u[b * 64 + i1] - u[b * 64 + i0]);
    float v0 = n0[t], v1 = n1[t];
    ci[(size_t)bp * 256 + t]       = 0.5f * (v0 + v1);
    ci[(size_t)bp * 256 + 128 + t] = s * v1 + (1.0f - s) * v0;
}

// -------- fused head: layer1 MFMA GEMM + ReLU + layer2 reduce --------------
// grid (64 rowblocks of 32 ci-rows, 3 heads). BN=512 (full head), K=256.
// LDS: B dbuf 2*64KB + A dbuf 2*4KB = 136 KB -> 1 block/CU.
__global__ __launch_bounds__(256, 1) void headcls_kernel(
    const float* __restrict__ ci,
    const short* __restrict__ Wf1_hi, const short* __restrict__ Wf1_lo,
    const float* __restrict__ b1a, const float* __restrict__ b1b,
    const float* __restrict__ b1c,
    const float* __restrict__ w2a, const float* __restrict__ w2b,
    const float* __restrict__ w2c,
    const float* __restrict__ b2a, const float* __restrict__ b2b,
    const float* __restrict__ b2c,
    float* __restrict__ out)
{
    __shared__ __align__(16) char smem[139264];
    // buf b: B_hi at b*65536 (32768 B), B_lo +32768; A at 131072+b*4096 (hi 2048, lo 2048)
    const int t = threadIdx.x;
    const int wv = t >> 6, lane = t & 63;
    const int rb = blockIdx.x;
    const int hd = blockIdx.y;
    const float* b1 = hd == 0 ? b1a : hd == 1 ? b1b : b1c;
    const float* w2 = hd == 0 ? w2a : hd == 1 ? w2b : w2c;
    const float* b2 = hd == 0 ? b2a : hd == 1 ? b2b : b2c;
    const int od  = hd == 0 ? 6 : hd == 1 ? 5 : 3;
    const int off = hd == 0 ? 0 : hd == 1 ? 6 : 11;

    const int arow = t >> 2, akb = t & 3;       // valid for t<128
    const int abyte = ((((arow >> 4) * 64) + ((akb << 4) | (arow & 15))) * 8) * 2;
    const float* aptr = ci + ((size_t)rb * 32 + arow) * 256 + akb * 8;

    f32x4 acc[2][8] = {};

    // prologue
    float4 a0, a1;
    if (t < 128) {
        a0 = *(const float4*)(aptr);
        a1 = *(const float4*)(aptr + 4);
    }
    {
        const char* sh = (const char*)(Wf1_hi + (size_t)hd * 8 * 32 * 512);
        const char* sl = (const char*)(Wf1_lo + (size_t)hd * 8 * 32 * 512);
#pragma unroll
        for (int i = 0; i < 8; ++i) {
            int ch = i * 4 + wv;
            int o2 = ch * 1024 + lane * 16;
            gload_lds16(sh + o2, smem + ch * 1024);
            gload_lds16(sl + o2, smem + 32768 + ch * 1024);
        }
    }
    if (t < 128) {
        float av[8] = {a0.x, a0.y, a0.z, a0.w, a1.x, a1.y, a1.z, a1.w};
        short8 h8, l8;
#pragma unroll
        for (int j = 0; j < 8; ++j) {
            short h = bf16_rne(av[j]);
            h8[j] = h;
            l8[j] = bf16_rne(av[j] - bf16_to_f(h));
        }
        *(short8*)(smem + 131072 + abyte) = h8;
        *(short8*)(smem + 131072 + 2048 + abyte) = l8;
    }
    __syncthreads();

    for (int kt = 0; kt < 8; ++kt) {
        const int cur = kt & 1;
        const char* Bh_c = smem + cur * 65536;
        const char* Bl_c = Bh_c + 32768;
        const char* Ah_c = smem + 131072 + cur * 4096;
        const char* Al_c = Ah_c + 2048;

        float4 b0, b1v;
        if (kt < 7) {
            const char* sh = (const char*)(Wf1_hi + ((size_t)hd * 8 + kt + 1) * 32 * 512);
            const char* sl = (const char*)(Wf1_lo + ((size_t)hd * 8 + kt + 1) * 32 * 512);
            char* dBh = smem + (cur ^ 1) * 65536;
#pragma unroll
            for (int i = 0; i < 8; ++i) {
                int ch = i * 4 + wv;
                int o2 = ch * 1024 + lane * 16;
                gload_lds16(sh + o2, dBh + ch * 1024);
                gload_lds16(sl + o2, dBh + 32768 + ch * 1024);
            }
            if (t < 128) {
                b0  = *(const float4*)(aptr + (size_t)(kt + 1) * 32);
                b1v = *(const float4*)(aptr + (size_t)(kt + 1) * 32 + 4);
            }
        }

        short8 Ah[2], Al[2];
#pragma unroll
        for (int rt = 0; rt < 2; ++rt) {
            Ah[rt] = *(const short8*)(Ah_c + (rt * 64 + lane) * 16);
            Al[rt] = *(const short8*)(Al_c + (rt * 64 + lane) * 16);
        }
#pragma unroll
        for (int c = 0; c < 8; ++c) {
            int ctg = wv * 8 + c;
            short8 Bh = *(const short8*)(Bh_c + (ctg * 64 + lane) * 16);
            short8 Bl = *(const short8*)(Bl_c + (ctg * 64 + lane) * 16);
#pragma unroll
            for (int rt = 0; rt < 2; ++rt) {
                acc[rt][c] = __builtin_amdgcn_mfma_f32_16x16x32_bf16(Ah[rt], Bh, acc[rt][c], 0, 0, 0);
                acc[rt][c] = __builtin_amdgcn_mfma_f32_16x16x32_bf16(Al[rt], Bh, acc[rt][c], 0, 0, 0);
                acc[rt][c] = __builtin_amdgcn_mfma_f32_16x16x32_bf16(Ah[rt], Bl, acc[rt][c], 0, 0, 0);
            }
        }

        if (kt < 7 && t < 128) {
            float av[8] = {b0.x, b0.y, b0.z, b0.w, b1v.x, b1v.y, b1v.z, b1v.w};
            short8 h8, l8;
#pragma unroll
            for (int j = 0; j < 8; ++j) {
                short h = bf16_rne(av[j]);
                h8[j] = h;
                l8[j] = bf16_rne(av[j] - bf16_to_f(h));
            }
            char* dAh = smem + 131072 + (cur ^ 1) * 4096;
            *(short8*)(dAh + abyte) = h8;
            *(short8*)(dAh + 2048 + abyte) = l8;
        }
        __syncthreads();
    }

    // ---- ReLU + bias -> h_s [32][516], then layer2 ----
    float* h_s = (float*)smem;
#pragma unroll
    for (int c = 0; c < 8; ++c) {
        int ctg = wv * 8 + c;
        int col = ctg * 16 + (lane & 15);
        float bias = b1[col];
#pragma unroll
        for (int rt = 0; rt < 2; ++rt) {
#pragma unroll
            for (int q = 0; q < 4; ++q) {
                int row = rt * 16 + ((lane >> 4) << 2) + q;
                h_s[row * 516 + col] = fmaxf(acc[rt][c][q] + bias, 0.f);
            }
        }
    }
    __syncthreads();

    {
        int row = t >> 3, o = t & 7;
        if (o < od) {
            const float* hr = h_s + row * 516;
            float a = b2[o];
            for (int c = 0; c < 512; ++c)
                a = fmaf(hr[c], w2[(size_t)c * od + o], a);
            out[((size_t)rb * 32 + row) * 14 + off + o] = a;
        }
    }
}

// ---------------------------------------------------------------------------
extern "C" void kernel_launch(void* const* d_in, const int* in_sizes, int n_in,
                              void* d_out, int out_size, void* d_ws, size_t ws_size,
                              hipStream_t stream)
{
    const float* x_edge   = (const float*)d_in[1];
    const float* et_w     = (const float*)d_in[6];
    const float* et_b     = (const float*)d_in[7];
    const float* egru_wih = (const float*)d_in[11];
    const float* egru_bih = (const float*)d_in[12];
    const float* egru_bhh = (const float*)d_in[13];
    const float* natt_w   = (const float*)d_in[14];
    const float* eatt_w   = (const float*)d_in[16];
    const float* lr_w1 = (const float*)d_in[18];
    const float* lr_b1 = (const float*)d_in[19];
    const float* lr_w2 = (const float*)d_in[20];
    const float* lr_b2 = (const float*)d_in[21];
    const float* cr_w1 = (const float*)d_in[22];
    const float* cr_b1 = (const float*)d_in[23];
    const float* cr_w2 = (const float*)d_in[24];
    const float* cr_b2 = (const float*)d_in[25];
    const float* mr_w1 = (const float*)d_in[26];
    const float* mr_b1 = (const float*)d_in[27];
    const float* mr_w2 = (const float*)d_in[28];
    const float* mr_b2 = (const float*)d_in[29];
    const int* pairs   = (const int*)d_in[30];
    float* out = (float*)d_out;
    char* ws = (char*)d_ws;

    // workspace layout (bytes)
    short* Wf_hi  = (short*)(ws + 0);          // 393216
    short* Wf_lo  = (short*)(ws + 393216);     // 393216
    short* Wf1_hi = (short*)(ws + 786432);     // 786432
    short* Wf1_lo = (short*)(ws + 1572864);    // 786432
    float* bc     = (float*)(ws + 2359296);    // 1536
    float* nh_p   = (float*)(ws + 2360832);    // 524288
    float* u      = (float*)(ws + 2885120);    // 4096
    float* ci     = (float*)(ws + 2889216);    // 2097152 (end 4986368)

    prep_w<<<768, 256, 0, stream>>>(et_w, egru_wih, Wf_hi, Wf_lo);
    prep_b<<<2, 256, 0, stream>>>(et_b, egru_wih, egru_bih, egru_bhh, bc);
    prep_w1<<<1536, 256, 0, stream>>>(lr_w1, cr_w1, mr_w1, Wf1_hi, Wf1_lo);

    mega_kernel<<<1024, 256, 0, stream>>>(
        x_edge, Wf_hi, Wf_lo, bc, egru_bhh, natt_w, eatt_w, nh_p, u);

    ci_kernel<<<2048, 128, 0, stream>>>(nh_p, u, pairs, ci);

    headcls_kernel<<<dim3(64, 3), 256, 0, stream>>>(
        ci, Wf1_hi, Wf1_lo, lr_b1, cr_b1, mr_b1,
        lr_w2, cr_w2, mr_w2, lr_b2, cr_b2, mr_b2, out);
}

// Round 5
// 145.298 us; speedup vs baseline: 1.3482x; 1.3482x over previous
//
#include <hip/hip_runtime.h>
#include <math.h>
#include <stdint.h>

// ---------------------------------------------------------------------------
// Algebraic reductions (verified, absmax 2.4e-4):
//  * 2-step loop idempotent -> run once; node branch cancels entirely.
//  * Composed GEMM: g = x_edge @ Wc + bc, Wc = et_w @ egru_wih^T [512,384].
//  * GRU gates + softmax-pool fused into GEMM epilogue.
//  * Heads: layer1 (bf16-split MFMA) + ReLU + layer2 fused in one kernel.
//  * Precision: split-bf16 (hi+lo) 3-term MFMA ~= f32 accuracy.
// Round-5 change: BM=128 (2 groups/block, 8 waves) halves L2 B-staging
// traffic (was the binding wall); B dbuf + A reg-prefetch + A dbuf -> ONE
// barrier per kt; 128 KB LDS, 2 waves/SIMD.
// ---------------------------------------------------------------------------

typedef __attribute__((ext_vector_type(8))) short short8;
typedef __attribute__((ext_vector_type(4))) float f32x4;

#define DEVINL __device__ __forceinline__

DEVINL float sigmoidf_(float x) { return 1.0f / (1.0f + __expf(-x)); }
DEVINL float tanhf_(float x) {
    float e = __expf(2.0f * x);
    return (e - 1.0f) / (e + 1.0f);
}
DEVINL short bf16_rne(float f) {
    uint32_t u = __float_as_uint(f);
    u += 0x7FFFu + ((u >> 16) & 1u);
    return (short)(u >> 16);
}
DEVINL float bf16_to_f(short s) {
    return __uint_as_float(((uint32_t)(uint16_t)s) << 16);
}
DEVINL void gload_lds16(const void* g, void* l) {
    __builtin_amdgcn_global_load_lds(
        (const __attribute__((address_space(1))) void*)(uintptr_t)g,
        (__attribute__((address_space(3))) void*)(uint32_t)(uintptr_t)l,
        16, 0, 0);
}

// ---------------- prep: Wc in MFMA fragment order, split hi/lo -------------
// Wc[k][n] = sum_m et_w[k][m] * egru_wih[n][m];  k<512, n<384.
// Layout: [kt(16)][plane(2: hi,lo)][ct(24)][lane(64)][j(8)] shorts,
//   k = kt*32 + ((lane>>4)&3)*8 + j,  n = ct*16 + (lane&15).
__global__ __launch_bounds__(256) void prep_w(
    const float* __restrict__ et_w, const float* __restrict__ wih,
    short* __restrict__ Wf)
{
    int idx = blockIdx.x * 256 + threadIdx.x;   // idx = n*512 + k
    int n = idx >> 9, k = idx & 511;
    const float4* a = (const float4*)(et_w + (size_t)k * 128);
    const float4* b = (const float4*)(wih + (size_t)n * 128);
    float acc = 0.f;
#pragma unroll 8
    for (int m = 0; m < 32; ++m) {
        float4 x = a[m], y = b[m];
        acc += x.x * y.x + x.y * y.y + x.z * y.z + x.w * y.w;
    }
    short h = bf16_rne(acc);
    short l = bf16_rne(acc - bf16_to_f(h));
    int kt = k >> 5, ct = n >> 4;
    int lanef = (((k >> 3) & 3) << 4) | (n & 15);
    int j = k & 7;
    size_t base = (size_t)kt * 24576 + ((size_t)ct * 64 + lanef) * 8 + j;
    Wf[base] = h;             // hi plane
    Wf[base + 12288] = l;     // lo plane
}

// bc[n] = et_b . egru_wih[n] + egru_bih[n] (+ egru_bhh[n] for n<256)
__global__ __launch_bounds__(256) void prep_b(
    const float* __restrict__ et_b, const float* __restrict__ wih,
    const float* __restrict__ bih, const float* __restrict__ bhh,
    float* __restrict__ bc)
{
    int n = blockIdx.x * 256 + threadIdx.x;
    if (n >= 384) return;
    float acc = bih[n] + (n < 256 ? bhh[n] : 0.f);
    const float* w = wih + (size_t)n * 128;
    for (int m = 0; m < 128; ++m) acc = fmaf(et_b[m], w[m], acc);
    bc[n] = acc;
}

// ---------------- prep: heads W1 (3x [256,512]) in fragment order ----------
__global__ __launch_bounds__(256) void prep_w1(
    const float* __restrict__ w1a, const float* __restrict__ w1b,
    const float* __restrict__ w1c,
    short* __restrict__ Wf1_hi, short* __restrict__ Wf1_lo)
{
    int idx = blockIdx.x * 256 + threadIdx.x;   // < 3*131072
    int h = idx >> 17;
    int r = idx & 131071;
    int k = r >> 9;
    int c = r & 511;
    const float* w1 = (h == 0) ? w1a : (h == 1) ? w1b : w1c;
    float v = w1[(size_t)k * 512 + c];
    short hi = bf16_rne(v);
    short lo = bf16_rne(v - bf16_to_f(hi));
    int kt = k >> 5, ct = c >> 4;
    int lane = (((k >> 3) & 3) << 4) | (c & 15);
    int j = k & 7;
    size_t fidx = ((((size_t)h * 8 + kt) * 32 + ct) * 64 + lane) * 8 + j;
    Wf1_hi[fidx] = hi;
    Wf1_lo[fidx] = lo;
}

// ---------------- mega: BM=128 GEMM + GRU gates + 2x softmax-pool ----------
// Block = 2 (b,i) groups: 128 rows x 384 cols, K=512 (16 kt of 32).
// 512 threads, 8 waves: wave(rq=wv>>2, cq=wv&3) = 64 rows x 96 cols.
// LDS: B dbuf 2*48KB @0, A dbuf 2*16KB @98304 -> 128 KB total.
__global__ __launch_bounds__(512, 2) void mega_kernel(
    const float* __restrict__ x_edge,
    const short* __restrict__ Wf,
    const float* __restrict__ bc, const float* __restrict__ bhh,
    const float* __restrict__ natt_w, const float* __restrict__ eatt_w,
    float* __restrict__ nh_p, float* __restrict__ u_out)
{
    __shared__ __align__(16) char smem[131072];
    const int t = threadIdx.x;
    const int wv = t >> 6, lane = t & 63;
    const int cq = wv & 3, rq = wv >> 2;
    const int g2 = blockIdx.x;
    const size_t bm = (size_t)g2 * 128;

    const int arow = t >> 2, akb = t & 3;
    const int aslotb = (((arow >> 4) * 64) + ((akb << 4) | (arow & 15))) * 16;
    const float* aptr = x_edge + (bm + arow) * 512 + akb * 8;

    f32x4 acc[4][6] = {};

    // ---- prologue: stage B(0) -> Bbuf0, A(0) -> Abuf0 ----
    {
        const char* src = (const char*)Wf;
#pragma unroll
        for (int i = 0; i < 6; ++i) {
            int off = (t + i * 512) * 16;
            gload_lds16(src + off, smem + off);
        }
        float4 a0 = *(const float4*)(aptr);
        float4 a1 = *(const float4*)(aptr + 4);
        float av[8] = {a0.x, a0.y, a0.z, a0.w, a1.x, a1.y, a1.z, a1.w};
        short8 h8, l8;
#pragma unroll
        for (int j = 0; j < 8; ++j) {
            short h = bf16_rne(av[j]);
            h8[j] = h;
            l8[j] = bf16_rne(av[j] - bf16_to_f(h));
        }
        *(short8*)(smem + 98304 + aslotb) = h8;
        *(short8*)(smem + 98304 + 8192 + aslotb) = l8;
    }
    __syncthreads();

    // ---- main loop: ONE barrier per kt ----
    for (int kt = 0; kt < 16; ++kt) {
        const int cur = kt & 1;
        float4 a0, a1;
        if (kt < 15) {
            const char* src = (const char*)Wf + (size_t)(kt + 1) * 49152;
            char* dst = smem + (cur ^ 1) * 49152;
#pragma unroll
            for (int i = 0; i < 6; ++i) {
                int off = (t + i * 512) * 16;
                gload_lds16(src + off, dst + off);
            }
            a0 = *(const float4*)(aptr + (size_t)(kt + 1) * 32);
            a1 = *(const float4*)(aptr + (size_t)(kt + 1) * 32 + 4);
        }

        const char* Bh_c = smem + cur * 49152;
        const char* Bl_c = Bh_c + 24576;
        const char* Ah_c = smem + 98304 + cur * 16384;
        const char* Al_c = Ah_c + 8192;

        short8 Ahf[4], Alf[4];
#pragma unroll
        for (int rt = 0; rt < 4; ++rt) {
            int grt = rq * 4 + rt;
            Ahf[rt] = *(const short8*)(Ah_c + (grt * 64 + lane) * 16);
            Alf[rt] = *(const short8*)(Al_c + (grt * 64 + lane) * 16);
        }
#pragma unroll
        for (int c = 0; c < 6; ++c) {
            int ctg = ((c >> 1) << 3) + (cq << 1) + (c & 1);
            short8 Bh = *(const short8*)(Bh_c + (ctg * 64 + lane) * 16);
            short8 Bl = *(const short8*)(Bl_c + (ctg * 64 + lane) * 16);
#pragma unroll
            for (int rt = 0; rt < 4; ++rt) {
                acc[rt][c] = __builtin_amdgcn_mfma_f32_16x16x32_bf16(Ahf[rt], Bh, acc[rt][c], 0, 0, 0);
                acc[rt][c] = __builtin_amdgcn_mfma_f32_16x16x32_bf16(Alf[rt], Bh, acc[rt][c], 0, 0, 0);
                acc[rt][c] = __builtin_amdgcn_mfma_f32_16x16x32_bf16(Ahf[rt], Bl, acc[rt][c], 0, 0, 0);
            }
        }

        if (kt < 15) {
            float av[8] = {a0.x, a0.y, a0.z, a0.w, a1.x, a1.y, a1.z, a1.w};
            short8 h8, l8;
#pragma unroll
            for (int j = 0; j < 8; ++j) {
                short h = bf16_rne(av[j]);
                h8[j] = h;
                l8[j] = bf16_rne(av[j] - bf16_to_f(h));
            }
            char* dAh = smem + 98304 + (cur ^ 1) * 16384;
            *(short8*)(dAh + aslotb) = h8;
            *(short8*)(dAh + 8192 + aslotb) = l8;
        }
        __syncthreads();
    }

    // ---- epilogue: two independent 256-thread teams (team = rq) ----
    const int EHP = 132;
    const int tt = cq * 64 + lane;              // team-local 0..255
    const int G = g2 * 2 + rq;                  // global group id
    float* eh_g = (float*)smem + rq * (64 * EHP);
    float* red  = (float*)(smem + 67584 + rq * 1536);
    float* s2v  = red + 256;
    float* ewv  = s2v + 64;

    // GRU gates -> eh_g
#pragma unroll
    for (int cc = 0; cc < 2; ++cc) {
        int o = (cq << 5) + (cc << 4) + (lane & 15);
        float bco = bc[o], bcz = bc[128 + o], bcn = bc[256 + o], bn3 = bhh[256 + o];
#pragma unroll
        for (int rt = 0; rt < 4; ++rt) {
#pragma unroll
            for (int q = 0; q < 4; ++q) {
                int row = rt * 16 + ((lane >> 4) << 2) + q;
                float r = sigmoidf_(acc[rt][cc][q] + bco);
                float z = sigmoidf_(acc[rt][2 + cc][q] + bcz);
                float n = tanhf_(acc[rt][4 + cc][q] + bcn + r * bn3);
                eh_g[row * EHP + o] = (1.0f - z) * n;
            }
        }
    }
    __syncthreads();

    // softmax-pool over j (64 rows) per team
    {
        int j = tt >> 2, q = tt & 3;
        const float* row = eh_g + j * EHP + q * 32;
        const float* wb = natt_w + 128 + q * 32;
        float a = 0.f;
#pragma unroll
        for (int k2 = 0; k2 < 32; ++k2) a = fmaf(row[k2], wb[k2], a);
        red[tt] = a;
    }
    __syncthreads();
    if (tt < 64) s2v[tt] = red[4 * tt] + red[4 * tt + 1] + red[4 * tt + 2] + red[4 * tt + 3];
    __syncthreads();
    if (tt < 64) {
        float m = -1e30f;
        for (int j = 0; j < 64; ++j) m = fmaxf(m, s2v[j]);
        ewv[tt] = __expf(s2v[tt] - m);
    }
    __syncthreads();
    float inv = 0.f;
    for (int j = 0; j < 64; ++j) inv += ewv[j];
    inv = 1.0f / inv;
    {
        int o = tt & 127, h = tt >> 7;
        float a = 0.f;
        for (int j = h * 32; j < h * 32 + 32; ++j)
            a = fmaf(ewv[j], eh_g[j * EHP + o], a);
        __syncthreads();
        red[tt] = a;
    }
    __syncthreads();
    if (tt < 128) {
        float v = (red[tt] + red[tt + 128]) * inv;
        nh_p[(size_t)G * 128 + tt] = v;
        red[tt] = v * eatt_w[tt];
    }
    __syncthreads();
    for (int s = 64; s > 0; s >>= 1) {
        if (tt < s) red[tt] += red[tt + s];
        __syncthreads();
    }
    if (tt == 0) u_out[G] = red[0];
}

// -------- classifier input --------------------------------------------------
__global__ __launch_bounds__(128) void ci_kernel(
    const float* __restrict__ nh_p, const float* __restrict__ u,
    const int* __restrict__ pairs, float* __restrict__ ci)
{
    const int bp = blockIdx.x;
    const int b  = bp >> 7;
    const int t  = threadIdx.x;
    int i0 = pairs[bp * 2 + 0];
    int i1 = pairs[bp * 2 + 1];
    const float* n0 = nh_p + (size_t)(b * 64 + i0) * 128;
    const float* n1 = nh_p + (size_t)(b * 64 + i1) * 128;
    float s = sigmoidf_(u[b * 64 + i1] - u[b * 64 + i0]);
    float v0 = n0[t], v1 = n1[t];
    ci[(size_t)bp * 256 + t]       = 0.5f * (v0 + v1);
    ci[(size_t)bp * 256 + 128 + t] = s * v1 + (1.0f - s) * v0;
}

// -------- fused head: layer1 MFMA GEMM + ReLU + layer2 reduce --------------
__global__ __launch_bounds__(256, 1) void headcls_kernel(
    const float* __restrict__ ci,
    const short* __restrict__ Wf1_hi, const short* __restrict__ Wf1_lo,
    const float* __restrict__ b1a, const float* __restrict__ b1b,
    const float* __restrict__ b1c,
    const float* __restrict__ w2a, const float* __restrict__ w2b,
    const float* __restrict__ w2c,
    const float* __restrict__ b2a, const float* __restrict__ b2b,
    const float* __restrict__ b2c,
    float* __restrict__ out)
{
    __shared__ __align__(16) char smem[139264];
    const int t = threadIdx.x;
    const int wv = t >> 6, lane = t & 63;
    const int rb = blockIdx.x;
    const int hd = blockIdx.y;
    const float* b1 = hd == 0 ? b1a : hd == 1 ? b1b : b1c;
    const float* w2 = hd == 0 ? w2a : hd == 1 ? w2b : w2c;
    const float* b2 = hd == 0 ? b2a : hd == 1 ? b2b : b2c;
    const int od  = hd == 0 ? 6 : hd == 1 ? 5 : 3;
    const int off = hd == 0 ? 0 : hd == 1 ? 6 : 11;

    const int arow = t >> 2, akb = t & 3;
    const int abyte = ((((arow >> 4) * 64) + ((akb << 4) | (arow & 15))) * 8) * 2;
    const float* aptr = ci + ((size_t)rb * 32 + arow) * 256 + akb * 8;

    f32x4 acc[2][8] = {};

    float4 a0, a1;
    if (t < 128) {
        a0 = *(const float4*)(aptr);
        a1 = *(const float4*)(aptr + 4);
    }
    {
        const char* sh = (const char*)(Wf1_hi + (size_t)hd * 8 * 32 * 512);
        const char* sl = (const char*)(Wf1_lo + (size_t)hd * 8 * 32 * 512);
#pragma unroll
        for (int i = 0; i < 8; ++i) {
            int ch = i * 4 + wv;
            int o2 = ch * 1024 + lane * 16;
            gload_lds16(sh + o2, smem + ch * 1024);
            gload_lds16(sl + o2, smem + 32768 + ch * 1024);
        }
    }
    if (t < 128) {
        float av[8] = {a0.x, a0.y, a0.z, a0.w, a1.x, a1.y, a1.z, a1.w};
        short8 h8, l8;
#pragma unroll
        for (int j = 0; j < 8; ++j) {
            short h = bf16_rne(av[j]);
            h8[j] = h;
            l8[j] = bf16_rne(av[j] - bf16_to_f(h));
        }
        *(short8*)(smem + 131072 + abyte) = h8;
        *(short8*)(smem + 131072 + 2048 + abyte) = l8;
    }
    __syncthreads();

    for (int kt = 0; kt < 8; ++kt) {
        const int cur = kt & 1;
        const char* Bh_c = smem + cur * 65536;
        const char* Bl_c = Bh_c + 32768;
        const char* Ah_c = smem + 131072 + cur * 4096;
        const char* Al_c = Ah_c + 2048;

        float4 b0, b1v;
        if (kt < 7) {
            const char* sh = (const char*)(Wf1_hi + ((size_t)hd * 8 + kt + 1) * 32 * 512);
            const char* sl = (const char*)(Wf1_lo + ((size_t)hd * 8 + kt + 1) * 32 * 512);
            char* dBh = smem + (cur ^ 1) * 65536;
#pragma unroll
            for (int i = 0; i < 8; ++i) {
                int ch = i * 4 + wv;
                int o2 = ch * 1024 + lane * 16;
                gload_lds16(sh + o2, dBh + ch * 1024);
                gload_lds16(sl + o2, dBh + 32768 + ch * 1024);
            }
            if (t < 128) {
                b0  = *(const float4*)(aptr + (size_t)(kt + 1) * 32);
                b1v = *(const float4*)(aptr + (size_t)(kt + 1) * 32 + 4);
            }
        }

        short8 Ah[2], Al[2];
#pragma unroll
        for (int rt = 0; rt < 2; ++rt) {
            Ah[rt] = *(const short8*)(Ah_c + (rt * 64 + lane) * 16);
            Al[rt] = *(const short8*)(Al_c + (rt * 64 + lane) * 16);
        }
#pragma unroll
        for (int c = 0; c < 8; ++c) {
            int ctg = wv * 8 + c;
            short8 Bh = *(const short8*)(Bh_c + (ctg * 64 + lane) * 16);
            short8 Bl = *(const short8*)(Bl_c + (ctg * 64 + lane) * 16);
#pragma unroll
            for (int rt = 0; rt < 2; ++rt) {
                acc[rt][c] = __builtin_amdgcn_mfma_f32_16x16x32_bf16(Ah[rt], Bh, acc[rt][c], 0, 0, 0);
                acc[rt][c] = __builtin_amdgcn_mfma_f32_16x16x32_bf16(Al[rt], Bh, acc[rt][c], 0, 0, 0);
                acc[rt][c] = __builtin_amdgcn_mfma_f32_16x16x32_bf16(Ah[rt], Bl, acc[rt][c], 0, 0, 0);
            }
        }

        if (kt < 7 && t < 128) {
            float av[8] = {b0.x, b0.y, b0.z, b0.w, b1v.x, b1v.y, b1v.z, b1v.w};
            short8 h8, l8;
#pragma unroll
            for (int j = 0; j < 8; ++j) {
                short h = bf16_rne(av[j]);
                h8[j] = h;
                l8[j] = bf16_rne(av[j] - bf16_to_f(h));
            }
            char* dAh = smem + 131072 + (cur ^ 1) * 4096;
            *(short8*)(dAh + abyte) = h8;
            *(short8*)(dAh + 2048 + abyte) = l8;
        }
        __syncthreads();
    }

    float* h_s = (float*)smem;
#pragma unroll
    for (int c = 0; c < 8; ++c) {
        int ctg = wv * 8 + c;
        int col = ctg * 16 + (lane & 15);
        float bias = b1[col];
#pragma unroll
        for (int rt = 0; rt < 2; ++rt) {
#pragma unroll
            for (int q = 0; q < 4; ++q) {
                int row = rt * 16 + ((lane >> 4) << 2) + q;
                h_s[row * 516 + col] = fmaxf(acc[rt][c][q] + bias, 0.f);
            }
        }
    }
    __syncthreads();

    {
        int row = t >> 3, o = t & 7;
        if (o < od) {
            const float* hr = h_s + row * 516;
            float a = b2[o];
            for (int c = 0; c < 512; ++c)
                a = fmaf(hr[c], w2[(size_t)c * od + o], a);
            out[((size_t)rb * 32 + row) * 14 + off + o] = a;
        }
    }
}

// ---------------------------------------------------------------------------
extern "C" void kernel_launch(void* const* d_in, const int* in_sizes, int n_in,
                              void* d_out, int out_size, void* d_ws, size_t ws_size,
                              hipStream_t stream)
{
    const float* x_edge   = (const float*)d_in[1];
    const float* et_w     = (const float*)d_in[6];
    const float* et_b     = (const float*)d_in[7];
    const float* egru_wih = (const float*)d_in[11];
    const float* egru_bih = (const float*)d_in[12];
    const float* egru_bhh = (const float*)d_in[13];
    const float* natt_w   = (const float*)d_in[14];
    const float* eatt_w   = (const float*)d_in[16];
    const float* lr_w1 = (const float*)d_in[18];
    const float* lr_b1 = (const float*)d_in[19];
    const float* lr_w2 = (const float*)d_in[20];
    const float* lr_b2 = (const float*)d_in[21];
    const float* cr_w1 = (const float*)d_in[22];
    const float* cr_b1 = (const float*)d_in[23];
    const float* cr_w2 = (const float*)d_in[24];
    const float* cr_b2 = (const float*)d_in[25];
    const float* mr_w1 = (const float*)d_in[26];
    const float* mr_b1 = (const float*)d_in[27];
    const float* mr_w2 = (const float*)d_in[28];
    const float* mr_b2 = (const float*)d_in[29];
    const int* pairs   = (const int*)d_in[30];
    float* out = (float*)d_out;
    char* ws = (char*)d_ws;

    // workspace layout (bytes)
    short* Wf     = (short*)(ws + 0);          // 786432 (hi/lo interleaved per kt)
    short* Wf1_hi = (short*)(ws + 786432);     // 786432
    short* Wf1_lo = (short*)(ws + 1572864);    // 786432
    float* bc     = (float*)(ws + 2359296);    // 1536
    float* nh_p   = (float*)(ws + 2360832);    // 524288
    float* u      = (float*)(ws + 2885120);    // 4096
    float* ci     = (float*)(ws + 2889216);    // 2097152 (end 4986368)

    prep_w<<<768, 256, 0, stream>>>(et_w, egru_wih, Wf);
    prep_b<<<2, 256, 0, stream>>>(et_b, egru_wih, egru_bih, egru_bhh, bc);
    prep_w1<<<1536, 256, 0, stream>>>(lr_w1, cr_w1, mr_w1, Wf1_hi, Wf1_lo);

    mega_kernel<<<512, 512, 0, stream>>>(
        x_edge, Wf, bc, egru_bhh, natt_w, eatt_w, nh_p, u);

    ci_kernel<<<2048, 128, 0, stream>>>(nh_p, u, pairs, ci);

    headcls_kernel<<<dim3(64, 3), 256, 0, stream>>>(
        ci, Wf1_hi, Wf1_lo, lr_b1, cr_b1, mr_b1,
        lr_w2, cr_w2, mr_w2, lr_b2, cr_b2, mr_b2, out);
}

// Round 6
// 111.631 us; speedup vs baseline: 1.7548x; 1.3016x over previous
//
#include <hip/hip_runtime.h>
#include <math.h>
#include <stdint.h>

// ---------------------------------------------------------------------------
// Algebraic reductions (verified, absmax 2.4e-4):
//  * 2-step loop idempotent -> run once; node branch cancels entirely.
//  * Factored (NOT composed) GEMM: Wc = et_w @ wih^T has rank 128 ->
//    edge_f = x_edge @ et_w + et_b  (8.6 GF), g = edge_f @ wih^T (6.4 GF)
//    beats the composed 25.8 GF. edge_f stored as packed hi/lo MFMA
//    A-fragments (33.5 MB, L3-resident between kernels).
//  * GRU gates + softmax-pool fused into g_kernel epilogue (block = group).
//  * Heads: layer1 (bf16-split MFMA) + ReLU + layer2 fused in one kernel.
//  * Precision: split-bf16 (hi+lo) 3-term MFMA ~= f32 accuracy.
// ---------------------------------------------------------------------------

typedef __attribute__((ext_vector_type(8))) short short8;
typedef __attribute__((ext_vector_type(4))) float f32x4;

#define DEVINL __device__ __forceinline__

DEVINL float sigmoidf_(float x) { return 1.0f / (1.0f + __expf(-x)); }
DEVINL float tanhf_(float x) {
    float e = __expf(2.0f * x);
    return (e - 1.0f) / (e + 1.0f);
}
DEVINL short bf16_rne(float f) {
    uint32_t u = __float_as_uint(f);
    u += 0x7FFFu + ((u >> 16) & 1u);
    return (short)(u >> 16);
}
DEVINL float bf16_to_f(short s) {
    return __uint_as_float(((uint32_t)(uint16_t)s) << 16);
}
DEVINL void gload_lds16(const void* g, void* l) {
    __builtin_amdgcn_global_load_lds(
        (const __attribute__((address_space(1))) void*)(uintptr_t)g,
        (__attribute__((address_space(3))) void*)(uint32_t)(uintptr_t)l,
        16, 0, 0);
}

// ---------------- prep: all weight fragment packing in one kernel ----------
// B-fragment layout convention (validated rounds 3-5): for n-col ct*16+(l&15),
// k = kt*32 + ((l>>4)&3)*8 + j.
// bid <256   : et_w [512,128] -> Bf1 [kt16][pl2][ct8][lane][j]
// bid 256-447: wih  [384,128] -> Bf2 [kt4][pl2][ct24][lane][j]
// bid >=448  : heads W1 (3x[256,512]) -> Wf1_hi/lo [h][kt8][ct32][lane][j]
__global__ __launch_bounds__(256) void prep_all(
    const float* __restrict__ et_w, const float* __restrict__ wih,
    const float* __restrict__ w1a, const float* __restrict__ w1b,
    const float* __restrict__ w1c,
    short* __restrict__ Bf1, short* __restrict__ Bf2,
    short* __restrict__ Wf1_hi, short* __restrict__ Wf1_lo)
{
    const int bid = blockIdx.x, t = threadIdx.x;
    if (bid < 256) {
        int idx = bid * 256 + t;            // [0,65536)
        int k = idx >> 7, n = idx & 127;
        float v = et_w[(size_t)k * 128 + n];
        short hi = bf16_rne(v), lo = bf16_rne(v - bf16_to_f(hi));
        int kt = k >> 5, ct = n >> 4;
        int lane = (((k >> 3) & 3) << 4) | (n & 15);
        int j = k & 7;
        size_t s0 = ((((size_t)kt * 2 + 0) * 8 + ct) * 64 + lane) * 8 + j;
        size_t s1 = ((((size_t)kt * 2 + 1) * 8 + ct) * 64 + lane) * 8 + j;
        Bf1[s0] = hi; Bf1[s1] = lo;
    } else if (bid < 448) {
        int idx = (bid - 256) * 256 + t;    // [0,49152)
        int n = idx >> 7, k = idx & 127;
        float v = wih[(size_t)n * 128 + k];
        short hi = bf16_rne(v), lo = bf16_rne(v - bf16_to_f(hi));
        int kt = k >> 5, ct = n >> 4;
        int lane = (((k >> 3) & 3) << 4) | (n & 15);
        int j = k & 7;
        size_t s0 = ((((size_t)kt * 2 + 0) * 24 + ct) * 64 + lane) * 8 + j;
        size_t s1 = ((((size_t)kt * 2 + 1) * 24 + ct) * 64 + lane) * 8 + j;
        Bf2[s0] = hi; Bf2[s1] = lo;
    } else {
        int idx = (bid - 448) * 256 + t;    // [0,393216)
        int h = idx >> 17;
        int r = idx & 131071;
        int k = r >> 9, c = r & 511;
        const float* w1 = (h == 0) ? w1a : (h == 1) ? w1b : w1c;
        float v = w1[(size_t)k * 512 + c];
        short hi = bf16_rne(v), lo = bf16_rne(v - bf16_to_f(hi));
        int kt = k >> 5, ct = c >> 4;
        int lane = (((k >> 3) & 3) << 4) | (c & 15);
        int j = k & 7;
        size_t fidx = ((((size_t)h * 8 + kt) * 32 + ct) * 64 + lane) * 8 + j;
        Wf1_hi[fidx] = hi;
        Wf1_lo[fidx] = lo;
    }
}

// ---------------- k1: edge_f = x_edge @ et_w + et_b -> A-fragments ---------
// BM=128, N=128, K=512 (16 kt). 512 thr, 8 waves (rq2 x cq4): 64r x 32c each.
// LDS: B dbuf 2*16KB @0, A dbuf 2*16KB @32768, etb @65536 -> 66048 B, 2/CU.
// Output EF per 64-row group: [kt2(4)][pl(2)][rt(4)][lane(64)][j(8)] shorts.
__global__ __launch_bounds__(512, 4) void ef_kernel(
    const float* __restrict__ x_edge, const short* __restrict__ Bf1,
    const float* __restrict__ et_b, short* __restrict__ EF)
{
    __shared__ __align__(16) char smem[66048];
    float* etb_s = (float*)(smem + 65536);
    const int t = threadIdx.x;
    const int wv = t >> 6, lane = t & 63;
    const int cq = wv & 3, rq = wv >> 2;
    const int g2 = blockIdx.x;
    const size_t bm = (size_t)g2 * 128;

    const int arow = t >> 2, akb = t & 3;
    const int aslotb = (((arow >> 4) * 64) + ((akb << 4) | (arow & 15))) * 16;
    const float* aptr = x_edge + (bm + arow) * 512 + akb * 8;

    f32x4 acc[4][2] = {};

    // prologue: stage B(0), A(0) into buf0
    if (t < 128) etb_s[t] = et_b[t];
    {
        const char* src = (const char*)Bf1;
#pragma unroll
        for (int i = 0; i < 2; ++i) {
            int off = (t + i * 512) * 16;
            gload_lds16(src + off, smem + off);
        }
        float4 a0 = *(const float4*)(aptr);
        float4 a1 = *(const float4*)(aptr + 4);
        float av[8] = {a0.x, a0.y, a0.z, a0.w, a1.x, a1.y, a1.z, a1.w};
        short8 h8, l8;
#pragma unroll
        for (int j = 0; j < 8; ++j) {
            short h = bf16_rne(av[j]);
            h8[j] = h;
            l8[j] = bf16_rne(av[j] - bf16_to_f(h));
        }
        *(short8*)(smem + 32768 + aslotb) = h8;
        *(short8*)(smem + 32768 + 8192 + aslotb) = l8;
    }
    __syncthreads();

    for (int kt = 0; kt < 16; ++kt) {
        const int cur = kt & 1;
        float4 a0, a1;
        if (kt < 15) {
            const char* src = (const char*)Bf1 + (size_t)(kt + 1) * 16384;
            char* dst = smem + (cur ^ 1) * 16384;
#pragma unroll
            for (int i = 0; i < 2; ++i) {
                int off = (t + i * 512) * 16;
                gload_lds16(src + off, dst + off);
            }
            a0 = *(const float4*)(aptr + (size_t)(kt + 1) * 32);
            a1 = *(const float4*)(aptr + (size_t)(kt + 1) * 32 + 4);
        }

        const char* Bb = smem + cur * 16384;
        const char* Ah_c = smem + 32768 + cur * 16384;
        const char* Al_c = Ah_c + 8192;

        short8 Ahf[4], Alf[4];
#pragma unroll
        for (int rt = 0; rt < 4; ++rt) {
            int grt = rq * 4 + rt;
            Ahf[rt] = *(const short8*)(Ah_c + (grt * 64 + lane) * 16);
            Alf[rt] = *(const short8*)(Al_c + (grt * 64 + lane) * 16);
        }
#pragma unroll
        for (int c = 0; c < 2; ++c) {
            int ct = cq * 2 + c;
            short8 Bh = *(const short8*)(Bb + (ct * 64 + lane) * 16);
            short8 Bl = *(const short8*)(Bb + 8192 + (ct * 64 + lane) * 16);
#pragma unroll
            for (int rt = 0; rt < 4; ++rt) {
                acc[rt][c] = __builtin_amdgcn_mfma_f32_16x16x32_bf16(Ahf[rt], Bh, acc[rt][c], 0, 0, 0);
                acc[rt][c] = __builtin_amdgcn_mfma_f32_16x16x32_bf16(Alf[rt], Bh, acc[rt][c], 0, 0, 0);
                acc[rt][c] = __builtin_amdgcn_mfma_f32_16x16x32_bf16(Ahf[rt], Bl, acc[rt][c], 0, 0, 0);
            }
        }

        if (kt < 15) {
            float av[8] = {a0.x, a0.y, a0.z, a0.w, a1.x, a1.y, a1.z, a1.w};
            short8 h8, l8;
#pragma unroll
            for (int j = 0; j < 8; ++j) {
                short h = bf16_rne(av[j]);
                h8[j] = h;
                l8[j] = bf16_rne(av[j] - bf16_to_f(h));
            }
            char* dAh = smem + 32768 + (cur ^ 1) * 16384;
            *(short8*)(dAh + aslotb) = h8;
            *(short8*)(dAh + 8192 + aslotb) = l8;
        }
        __syncthreads();
    }

    // ---- epilogue: C-layout -> A-fragment transpose via LDS, 2 halves ----
    float* ef_s = (float*)smem;     // [64][132] f32 = 33792 B
#pragma unroll
    for (int h = 0; h < 2; ++h) {
        if (h) __syncthreads();
        if (rq == h) {
#pragma unroll
            for (int c = 0; c < 2; ++c) {
                int col = cq * 32 + c * 16 + (lane & 15);
                float bias = etb_s[col];
#pragma unroll
                for (int rt = 0; rt < 4; ++rt) {
#pragma unroll
                    for (int q = 0; q < 4; ++q) {
                        int row = rt * 16 + ((lane >> 4) << 2) + q;
                        ef_s[row * 132 + col] = acc[rt][c][q] + bias;
                    }
                }
            }
        }
        __syncthreads();
        const size_t group = (size_t)g2 * 2 + h;
#pragma unroll
        for (int u2 = 0; u2 < 2; ++u2) {
            int unit = t + u2 * 512;            // (kt2*4+rt)*64 + ln
            int kt2 = unit >> 8;
            int rt = (unit >> 6) & 3;
            int ln = unit & 63;
            int row = rt * 16 + (ln & 15);
            int feat0 = kt2 * 32 + (ln >> 4) * 8;
            const float* src = ef_s + row * 132 + feat0;
            float4 v0 = *(const float4*)(src);
            float4 v1 = *(const float4*)(src + 4);
            float av[8] = {v0.x, v0.y, v0.z, v0.w, v1.x, v1.y, v1.z, v1.w};
            short8 h8, l8;
#pragma unroll
            for (int j = 0; j < 8; ++j) {
                short hh = bf16_rne(av[j]);
                h8[j] = hh;
                l8[j] = bf16_rne(av[j] - bf16_to_f(hh));
            }
            short* dst = EF + group * 16384;
            *(short8*)(dst + (((kt2 * 2 + 0) * 4 + rt) * 64 + ln) * 8) = h8;
            *(short8*)(dst + (((kt2 * 2 + 1) * 4 + rt) * 64 + ln) * 8) = l8;
        }
    }
}

// ---------------- k2: g = edge_f @ wih^T + gates + softmax-pool ------------
// Block = one (b,i) group: 64 rows x 384 cols, K=128 (4 kt).
// 256 thr, 4 waves; wave wv owns gate cols o in [wv*32, wv*32+32).
// LDS: A frags 32KB @0 (staged once), B single-buf 48KB @32768 -> 80 KB, 2/CU.
__global__ __launch_bounds__(256, 2) void g_kernel(
    const short* __restrict__ EF, const short* __restrict__ Bf2,
    const float* __restrict__ bih, const float* __restrict__ bhh,
    const float* __restrict__ natt_w, const float* __restrict__ eatt_w,
    float* __restrict__ nh_p, float* __restrict__ u_out)
{
    __shared__ __align__(16) char smem[81920];
    const int t = threadIdx.x;
    const int wv = t >> 6, lane = t & 63;
    const int g = blockIdx.x;

    // stage A (32 KB, linear)
    {
        const char* src = (const char*)(EF + (size_t)g * 16384);
#pragma unroll
        for (int i = 0; i < 8; ++i) {
            int off = (t + i * 256) * 16;
            gload_lds16(src + off, smem + off);
        }
    }

    f32x4 acc[4][6] = {};

    for (int kt = 0; kt < 4; ++kt) {
        // stage B(kt): 48 KB linear
        {
            const char* src = (const char*)Bf2 + (size_t)kt * 49152;
#pragma unroll
            for (int i = 0; i < 12; ++i) {
                int off = (t + i * 256) * 16;
                gload_lds16(src + off, smem + 32768 + off);
            }
        }
        __syncthreads();

        const char* Ab = smem + kt * 8192;
        short8 Ahf[4], Alf[4];
#pragma unroll
        for (int rt = 0; rt < 4; ++rt) {
            Ahf[rt] = *(const short8*)(Ab + (rt * 64 + lane) * 16);
            Alf[rt] = *(const short8*)(Ab + 4096 + (rt * 64 + lane) * 16);
        }
#pragma unroll
        for (int c = 0; c < 6; ++c) {
            int ctg = ((c >> 1) << 3) + (wv << 1) + (c & 1);
            short8 Bh = *(const short8*)(smem + 32768 + (ctg * 64 + lane) * 16);
            short8 Bl = *(const short8*)(smem + 32768 + 24576 + (ctg * 64 + lane) * 16);
#pragma unroll
            for (int rt = 0; rt < 4; ++rt) {
                acc[rt][c] = __builtin_amdgcn_mfma_f32_16x16x32_bf16(Ahf[rt], Bh, acc[rt][c], 0, 0, 0);
                acc[rt][c] = __builtin_amdgcn_mfma_f32_16x16x32_bf16(Alf[rt], Bh, acc[rt][c], 0, 0, 0);
                acc[rt][c] = __builtin_amdgcn_mfma_f32_16x16x32_bf16(Ahf[rt], Bl, acc[rt][c], 0, 0, 0);
            }
        }
        __syncthreads();
    }

    // ---- epilogue: GRU gates -> eh_s, softmax-pool (round-3 validated) ----
    const int EHP = 132;
    float* eh_s = (float*)(smem + 32768);           // [64][132]
    float* red  = (float*)(smem + 32768 + 33792);   // 256 f
    float* s2v  = red + 256;
    float* ewv  = s2v + 64;
#pragma unroll
    for (int cc = 0; cc < 2; ++cc) {
        int o = (wv << 5) + (cc << 4) + (lane & 15);
        float bco = bih[o] + bhh[o];
        float bcz = bih[128 + o] + bhh[128 + o];
        float bcn = bih[256 + o];
        float bn3 = bhh[256 + o];
#pragma unroll
        for (int rt = 0; rt < 4; ++rt) {
#pragma unroll
            for (int q = 0; q < 4; ++q) {
                int row = rt * 16 + ((lane >> 4) << 2) + q;
                float r = sigmoidf_(acc[rt][cc][q] + bco);
                float z = sigmoidf_(acc[rt][2 + cc][q] + bcz);
                float n = tanhf_(acc[rt][4 + cc][q] + bcn + r * bn3);
                eh_s[row * EHP + o] = (1.0f - z) * n;
            }
        }
    }
    __syncthreads();

    {
        int j = t >> 2, q = t & 3;
        const float* row = eh_s + j * EHP + q * 32;
        const float* wb = natt_w + 128 + q * 32;
        float a = 0.f;
#pragma unroll
        for (int k2 = 0; k2 < 32; ++k2) a = fmaf(row[k2], wb[k2], a);
        red[t] = a;
    }
    __syncthreads();
    if (t < 64) s2v[t] = red[4 * t] + red[4 * t + 1] + red[4 * t + 2] + red[4 * t + 3];
    __syncthreads();
    if (t < 64) {
        float m = -1e30f;
        for (int j = 0; j < 64; ++j) m = fmaxf(m, s2v[j]);
        ewv[t] = __expf(s2v[t] - m);
    }
    __syncthreads();
    float inv = 0.f;
    for (int j = 0; j < 64; ++j) inv += ewv[j];
    inv = 1.0f / inv;
    {
        int o = t & 127, h = t >> 7;
        float a = 0.f;
        for (int j = h * 32; j < h * 32 + 32; ++j)
            a = fmaf(ewv[j], eh_s[j * EHP + o], a);
        __syncthreads();
        red[t] = a;
    }
    __syncthreads();
    if (t < 128) {
        float v = (red[t] + red[t + 128]) * inv;
        nh_p[(size_t)g * 128 + t] = v;
        red[t] = v * eatt_w[t];
    }
    __syncthreads();
    for (int s = 64; s > 0; s >>= 1) {
        if (t < s) red[t] += red[t + s];
        __syncthreads();
    }
    if (t == 0) u_out[g] = red[0];
}

// -------- classifier input --------------------------------------------------
__global__ __launch_bounds__(128) void ci_kernel(
    const float* __restrict__ nh_p, const float* __restrict__ u,
    const int* __restrict__ pairs, float* __restrict__ ci)
{
    const int bp = blockIdx.x;
    const int b  = bp >> 7;
    const int t  = threadIdx.x;
    int i0 = pairs[bp * 2 + 0];
    int i1 = pairs[bp * 2 + 1];
    const float* n0 = nh_p + (size_t)(b * 64 + i0) * 128;
    const float* n1 = nh_p + (size_t)(b * 64 + i1) * 128;
    float s = sigmoidf_(u[b * 64 + i1] - u[b * 64 + i0]);
    float v0 = n0[t], v1 = n1[t];
    ci[(size_t)bp * 256 + t]       = 0.5f * (v0 + v1);
    ci[(size_t)bp * 256 + 128 + t] = s * v1 + (1.0f - s) * v0;
}

// -------- fused head: layer1 MFMA GEMM + ReLU + layer2 reduce --------------
__global__ __launch_bounds__(256, 1) void headcls_kernel(
    const float* __restrict__ ci,
    const short* __restrict__ Wf1_hi, const short* __restrict__ Wf1_lo,
    const float* __restrict__ b1a, const float* __restrict__ b1b,
    const float* __restrict__ b1c,
    const float* __restrict__ w2a, const float* __restrict__ w2b,
    const float* __restrict__ w2c,
    const float* __restrict__ b2a, const float* __restrict__ b2b,
    const float* __restrict__ b2c,
    float* __restrict__ out)
{
    __shared__ __align__(16) char smem[139264];
    const int t = threadIdx.x;
    const int wv = t >> 6, lane = t & 63;
    const int rb = blockIdx.x;
    const int hd = blockIdx.y;
    const float* b1 = hd == 0 ? b1a : hd == 1 ? b1b : b1c;
    const float* w2 = hd == 0 ? w2a : hd == 1 ? w2b : w2c;
    const float* b2 = hd == 0 ? b2a : hd == 1 ? b2b : b2c;
    const int od  = hd == 0 ? 6 : hd == 1 ? 5 : 3;
    const int off = hd == 0 ? 0 : hd == 1 ? 6 : 11;

    const int arow = t >> 2, akb = t & 3;
    const int abyte = ((((arow >> 4) * 64) + ((akb << 4) | (arow & 15))) * 8) * 2;
    const float* aptr = ci + ((size_t)rb * 32 + arow) * 256 + akb * 8;

    f32x4 acc[2][8] = {};

    float4 a0, a1;
    if (t < 128) {
        a0 = *(const float4*)(aptr);
        a1 = *(const float4*)(aptr + 4);
    }
    {
        const char* sh = (const char*)(Wf1_hi + (size_t)hd * 8 * 32 * 512);
        const char* sl = (const char*)(Wf1_lo + (size_t)hd * 8 * 32 * 512);
#pragma unroll
        for (int i = 0; i < 8; ++i) {
            int ch = i * 4 + wv;
            int o2 = ch * 1024 + lane * 16;
            gload_lds16(sh + o2, smem + ch * 1024);
            gload_lds16(sl + o2, smem + 32768 + ch * 1024);
        }
    }
    if (t < 128) {
        float av[8] = {a0.x, a0.y, a0.z, a0.w, a1.x, a1.y, a1.z, a1.w};
        short8 h8, l8;
#pragma unroll
        for (int j = 0; j < 8; ++j) {
            short h = bf16_rne(av[j]);
            h8[j] = h;
            l8[j] = bf16_rne(av[j] - bf16_to_f(h));
        }
        *(short8*)(smem + 131072 + abyte) = h8;
        *(short8*)(smem + 131072 + 2048 + abyte) = l8;
    }
    __syncthreads();

    for (int kt = 0; kt < 8; ++kt) {
        const int cur = kt & 1;
        const char* Bh_c = smem + cur * 65536;
        const char* Bl_c = Bh_c + 32768;
        const char* Ah_c = smem + 131072 + cur * 4096;
        const char* Al_c = Ah_c + 2048;

        float4 b0, b1v;
        if (kt < 7) {
            const char* sh = (const char*)(Wf1_hi + ((size_t)hd * 8 + kt + 1) * 32 * 512);
            const char* sl = (const char*)(Wf1_lo + ((size_t)hd * 8 + kt + 1) * 32 * 512);
            char* dBh = smem + (cur ^ 1) * 65536;
#pragma unroll
            for (int i = 0; i < 8; ++i) {
                int ch = i * 4 + wv;
                int o2 = ch * 1024 + lane * 16;
                gload_lds16(sh + o2, dBh + ch * 1024);
                gload_lds16(sl + o2, dBh + 32768 + ch * 1024);
            }
            if (t < 128) {
                b0  = *(const float4*)(aptr + (size_t)(kt + 1) * 32);
                b1v = *(const float4*)(aptr + (size_t)(kt + 1) * 32 + 4);
            }
        }

        short8 Ah[2], Al[2];
#pragma unroll
        for (int rt = 0; rt < 2; ++rt) {
            Ah[rt] = *(const short8*)(Ah_c + (rt * 64 + lane) * 16);
            Al[rt] = *(const short8*)(Al_c + (rt * 64 + lane) * 16);
        }
#pragma unroll
        for (int c = 0; c < 8; ++c) {
            int ctg = wv * 8 + c;
            short8 Bh = *(const short8*)(Bh_c + (ctg * 64 + lane) * 16);
            short8 Bl = *(const short8*)(Bl_c + (ctg * 64 + lane) * 16);
#pragma unroll
            for (int rt = 0; rt < 2; ++rt) {
                acc[rt][c] = __builtin_amdgcn_mfma_f32_16x16x32_bf16(Ah[rt], Bh, acc[rt][c], 0, 0, 0);
                acc[rt][c] = __builtin_amdgcn_mfma_f32_16x16x32_bf16(Al[rt], Bh, acc[rt][c], 0, 0, 0);
                acc[rt][c] = __builtin_amdgcn_mfma_f32_16x16x32_bf16(Ah[rt], Bl, acc[rt][c], 0, 0, 0);
            }
        }

        if (kt < 7 && t < 128) {
            float av[8] = {b0.x, b0.y, b0.z, b0.w, b1v.x, b1v.y, b1v.z, b1v.w};
            short8 h8, l8;
#pragma unroll
            for (int j = 0; j < 8; ++j) {
                short h = bf16_rne(av[j]);
                h8[j] = h;
                l8[j] = bf16_rne(av[j] - bf16_to_f(h));
            }
            char* dAh = smem + 131072 + (cur ^ 1) * 4096;
            *(short8*)(dAh + abyte) = h8;
            *(short8*)(dAh + 2048 + abyte) = l8;
        }
        __syncthreads();
    }

    float* h_s = (float*)smem;
#pragma unroll
    for (int c = 0; c < 8; ++c) {
        int ctg = wv * 8 + c;
        int col = ctg * 16 + (lane & 15);
        float bias = b1[col];
#pragma unroll
        for (int rt = 0; rt < 2; ++rt) {
#pragma unroll
            for (int q = 0; q < 4; ++q) {
                int row = rt * 16 + ((lane >> 4) << 2) + q;
                h_s[row * 516 + col] = fmaxf(acc[rt][c][q] + bias, 0.f);
            }
        }
    }
    __syncthreads();

    {
        int row = t >> 3, o = t & 7;
        if (o < od) {
            const float* hr = h_s + row * 516;
            float a = b2[o];
            for (int c = 0; c < 512; ++c)
                a = fmaf(hr[c], w2[(size_t)c * od + o], a);
            out[((size_t)rb * 32 + row) * 14 + off + o] = a;
        }
    }
}

// ---------------------------------------------------------------------------
extern "C" void kernel_launch(void* const* d_in, const int* in_sizes, int n_in,
                              void* d_out, int out_size, void* d_ws, size_t ws_size,
                              hipStream_t stream)
{
    const float* x_edge   = (const float*)d_in[1];
    const float* et_w     = (const float*)d_in[6];
    const float* et_b     = (const float*)d_in[7];
    const float* egru_wih = (const float*)d_in[11];
    const float* egru_bih = (const float*)d_in[12];
    const float* egru_bhh = (const float*)d_in[13];
    const float* natt_w   = (const float*)d_in[14];
    const float* eatt_w   = (const float*)d_in[16];
    const float* lr_w1 = (const float*)d_in[18];
    const float* lr_b1 = (const float*)d_in[19];
    const float* lr_w2 = (const float*)d_in[20];
    const float* lr_b2 = (const float*)d_in[21];
    const float* cr_w1 = (const float*)d_in[22];
    const float* cr_b1 = (const float*)d_in[23];
    const float* cr_w2 = (const float*)d_in[24];
    const float* cr_b2 = (const float*)d_in[25];
    const float* mr_w1 = (const float*)d_in[26];
    const float* mr_b1 = (const float*)d_in[27];
    const float* mr_w2 = (const float*)d_in[28];
    const float* mr_b2 = (const float*)d_in[29];
    const int* pairs   = (const int*)d_in[30];
    float* out = (float*)d_out;
    char* ws = (char*)d_ws;

    // workspace layout (bytes)
    short* Bf1    = (short*)(ws + 0);          // 262144
    short* Bf2    = (short*)(ws + 262144);     // 196608
    short* Wf1_hi = (short*)(ws + 458752);     // 786432
    short* Wf1_lo = (short*)(ws + 1245184);    // 786432
    float* nh_p   = (float*)(ws + 2031616);    // 524288
    float* u      = (float*)(ws + 2555904);    // 4096
    float* ci     = (float*)(ws + 2560000);    // 2097152 -> end 4657152
    const size_t FIXED = 4657152;
    short* EF     = (short*)(ws + FIXED);      // up to 33554432 B

    int CH = 1;
    while (CH < 16 && FIXED + (size_t)(33554432 / CH) > ws_size) CH <<= 1;
    const int blocks1 = 512 / CH;              // ef blocks per chunk (128 rows)
    const int groupsC = 1024 / CH;             // groups per chunk

    prep_all<<<1984, 256, 0, stream>>>(et_w, egru_wih, lr_w1, cr_w1, mr_w1,
                                       Bf1, Bf2, Wf1_hi, Wf1_lo);

    for (int c = 0; c < CH; ++c) {
        const float* xe = x_edge + (size_t)c * blocks1 * 128 * 512;
        ef_kernel<<<blocks1, 512, 0, stream>>>(xe, Bf1, et_b, EF);
        g_kernel<<<groupsC, 256, 0, stream>>>(
            EF, Bf2, egru_bih, egru_bhh, natt_w, eatt_w,
            nh_p + (size_t)c * groupsC * 128, u + (size_t)c * groupsC);
    }

    ci_kernel<<<2048, 128, 0, stream>>>(nh_p, u, pairs, ci);

    headcls_kernel<<<dim3(64, 3), 256, 0, stream>>>(
        ci, Wf1_hi, Wf1_lo, lr_b1, cr_b1, mr_b1,
        lr_w2, cr_w2, mr_w2, lr_b2, cr_b2, mr_b2, out);
}

// Round 7
// 100.918 us; speedup vs baseline: 1.9411x; 1.1062x over previous
//
#include <hip/hip_runtime.h>
#include <math.h>
#include <stdint.h>

// ---------------------------------------------------------------------------
// Algebraic reductions (verified, absmax 2.4e-4):
//  * 2-step loop idempotent -> run once; node branch cancels entirely.
//  * Factored GEMM (rank-128): edge_f = x_edge @ et_w (8.6 GF), then
//    g = edge_f @ wih^T (6.4 GF) — beats composed 25.8 GF.
//  * Round-7: FULLY FUSED. edge_f never leaves the block: phase1 ef GEMM
//    (dbuf pipeline) -> phase2 LDS transpose to A-fragments -> phase3 g GEMM
//    -> GRU gates + softmax-pool epilogue. 80 KB LDS exactly -> 2 blocks/CU.
//  * Heads: layer1 (bf16-split MFMA) + ReLU + layer2 (w2 in LDS) fused.
//  * Precision: split-bf16 (hi+lo) 3-term MFMA ~= f32 accuracy.
// ---------------------------------------------------------------------------

typedef __attribute__((ext_vector_type(8))) short short8;
typedef __attribute__((ext_vector_type(4))) float f32x4;

#define DEVINL __device__ __forceinline__

DEVINL float sigmoidf_(float x) { return 1.0f / (1.0f + __expf(-x)); }
DEVINL float tanhf_(float x) {
    float e = __expf(2.0f * x);
    return (e - 1.0f) / (e + 1.0f);
}
DEVINL short bf16_rne(float f) {
    uint32_t u = __float_as_uint(f);
    u += 0x7FFFu + ((u >> 16) & 1u);
    return (short)(u >> 16);
}
DEVINL float bf16_to_f(short s) {
    return __uint_as_float(((uint32_t)(uint16_t)s) << 16);
}
DEVINL void gload_lds16(const void* g, void* l) {
    __builtin_amdgcn_global_load_lds(
        (const __attribute__((address_space(1))) void*)(uintptr_t)g,
        (__attribute__((address_space(3))) void*)(uint32_t)(uintptr_t)l,
        16, 0, 0);
}

// ---------------- prep: all weight fragment packing in one kernel ----------
// B-fragment convention (validated r3-r6): col n = ct*16+(l&15),
// k = kt*32 + ((l>>4)&3)*8 + j.
// bid <256   : et_w [512,128] -> Bf1 [kt16][pl2][ct8][lane][j]
// bid 256-447: wih  [384,128] -> Bf2 [kt4][pl2][ct24][lane][j]
// bid >=448  : heads W1 (3x[256,512]) -> Wf1_hi/lo [h][kt8][ct32][lane][j]
__global__ __launch_bounds__(256) void prep_all(
    const float* __restrict__ et_w, const float* __restrict__ wih,
    const float* __restrict__ w1a, const float* __restrict__ w1b,
    const float* __restrict__ w1c,
    short* __restrict__ Bf1, short* __restrict__ Bf2,
    short* __restrict__ Wf1_hi, short* __restrict__ Wf1_lo)
{
    const int bid = blockIdx.x, t = threadIdx.x;
    if (bid < 256) {
        int idx = bid * 256 + t;            // [0,65536)
        int k = idx >> 7, n = idx & 127;
        float v = et_w[(size_t)k * 128 + n];
        short hi = bf16_rne(v), lo = bf16_rne(v - bf16_to_f(hi));
        int kt = k >> 5, ct = n >> 4;
        int lane = (((k >> 3) & 3) << 4) | (n & 15);
        int j = k & 7;
        size_t s0 = ((((size_t)kt * 2 + 0) * 8 + ct) * 64 + lane) * 8 + j;
        size_t s1 = ((((size_t)kt * 2 + 1) * 8 + ct) * 64 + lane) * 8 + j;
        Bf1[s0] = hi; Bf1[s1] = lo;
    } else if (bid < 448) {
        int idx = (bid - 256) * 256 + t;    // [0,49152)
        int n = idx >> 7, k = idx & 127;
        float v = wih[(size_t)n * 128 + k];
        short hi = bf16_rne(v), lo = bf16_rne(v - bf16_to_f(hi));
        int kt = k >> 5, ct = n >> 4;
        int lane = (((k >> 3) & 3) << 4) | (n & 15);
        int j = k & 7;
        size_t s0 = ((((size_t)kt * 2 + 0) * 24 + ct) * 64 + lane) * 8 + j;
        size_t s1 = ((((size_t)kt * 2 + 1) * 24 + ct) * 64 + lane) * 8 + j;
        Bf2[s0] = hi; Bf2[s1] = lo;
    } else {
        int idx = (bid - 448) * 256 + t;    // [0,393216)
        int h = idx >> 17;
        int r = idx & 131071;
        int k = r >> 9, c = r & 511;
        const float* w1 = (h == 0) ? w1a : (h == 1) ? w1b : w1c;
        float v = w1[(size_t)k * 512 + c];
        short hi = bf16_rne(v), lo = bf16_rne(v - bf16_to_f(hi));
        int kt = k >> 5, ct = c >> 4;
        int lane = (((k >> 3) & 3) << 4) | (c & 15);
        int j = k & 7;
        size_t fidx = ((((size_t)h * 8 + kt) * 32 + ct) * 64 + lane) * 8 + j;
        Wf1_hi[fidx] = hi;
        Wf1_lo[fidx] = lo;
    }
}

// ---------------- fused: ef GEMM -> transpose -> g GEMM -> gates+pool ------
// Block = one (b,i) group (64 rows). 256 thr, 4 waves.
// LDS map (80 KB total, 2 blocks/CU):
//  phase1: B dbuf 2*16KB @0, A dbuf 2*8KB @32768..49152
//  phase2: ef_s [64][132] f32 @0 (overlay); AF (A-frags) 32KB @49152
//  phase3: Bf2 tile 48KB @0 (overlay); AF @49152 persists
//  epilogue: eh_s [64][132] @0 + red/s2v/ewv @33792
__global__ __launch_bounds__(256, 2) void fused_kernel(
    const float* __restrict__ x_edge,
    const short* __restrict__ Bf1, const short* __restrict__ Bf2,
    const float* __restrict__ et_b,
    const float* __restrict__ bih, const float* __restrict__ bhh,
    const float* __restrict__ natt_w, const float* __restrict__ eatt_w,
    float* __restrict__ nh_p, float* __restrict__ u_out)
{
    __shared__ __align__(16) char smem[81920];
    const int t = threadIdx.x;
    const int wv = t >> 6, lane = t & 63;
    const int g = blockIdx.x;
    const size_t bm = (size_t)g * 64;

    const int arow = t >> 2, akb = t & 3;
    const int aslotb = (((arow >> 4) * 64) + ((akb << 4) | (arow & 15))) * 16;
    const float* aptr = x_edge + (bm + arow) * 512 + akb * 8;

    f32x4 acc1[4][2] = {};

    // ---- phase 1 prologue: stage B(0), A(0) into buf0 ----
    {
        const char* src = (const char*)Bf1;
#pragma unroll
        for (int i = 0; i < 4; ++i) {
            int off = (t + i * 256) * 16;
            gload_lds16(src + off, smem + off);
        }
        float4 a0 = *(const float4*)(aptr);
        float4 a1 = *(const float4*)(aptr + 4);
        float av[8] = {a0.x, a0.y, a0.z, a0.w, a1.x, a1.y, a1.z, a1.w};
        short8 h8, l8;
#pragma unroll
        for (int j = 0; j < 8; ++j) {
            short h = bf16_rne(av[j]);
            h8[j] = h;
            l8[j] = bf16_rne(av[j] - bf16_to_f(h));
        }
        *(short8*)(smem + 32768 + aslotb) = h8;
        *(short8*)(smem + 32768 + 4096 + aslotb) = l8;
    }
    __syncthreads();

    // ---- phase 1 main loop: stage(kt+1) || compute(kt), one barrier/kt ----
    for (int kt = 0; kt < 16; ++kt) {
        const int cur = kt & 1;
        float4 a0, a1;
        if (kt < 15) {
            const char* src = (const char*)Bf1 + (size_t)(kt + 1) * 16384;
            char* dst = smem + (cur ^ 1) * 16384;
#pragma unroll
            for (int i = 0; i < 4; ++i) {
                int off = (t + i * 256) * 16;
                gload_lds16(src + off, dst + off);
            }
            a0 = *(const float4*)(aptr + (size_t)(kt + 1) * 32);
            a1 = *(const float4*)(aptr + (size_t)(kt + 1) * 32 + 4);
        }

        const char* Bb = smem + cur * 16384;
        const char* Ah_c = smem + 32768 + cur * 8192;
        const char* Al_c = Ah_c + 4096;

        short8 Ahf[4], Alf[4];
#pragma unroll
        for (int rt = 0; rt < 4; ++rt) {
            Ahf[rt] = *(const short8*)(Ah_c + (rt * 64 + lane) * 16);
            Alf[rt] = *(const short8*)(Al_c + (rt * 64 + lane) * 16);
        }
#pragma unroll
        for (int c = 0; c < 2; ++c) {
            int ct = wv * 2 + c;
            short8 Bh = *(const short8*)(Bb + (ct * 64 + lane) * 16);
            short8 Bl = *(const short8*)(Bb + 8192 + (ct * 64 + lane) * 16);
#pragma unroll
            for (int rt = 0; rt < 4; ++rt) {
                acc1[rt][c] = __builtin_amdgcn_mfma_f32_16x16x32_bf16(Ahf[rt], Bh, acc1[rt][c], 0, 0, 0);
                acc1[rt][c] = __builtin_amdgcn_mfma_f32_16x16x32_bf16(Alf[rt], Bh, acc1[rt][c], 0, 0, 0);
                acc1[rt][c] = __builtin_amdgcn_mfma_f32_16x16x32_bf16(Ahf[rt], Bl, acc1[rt][c], 0, 0, 0);
            }
        }

        if (kt < 15) {
            float av[8] = {a0.x, a0.y, a0.z, a0.w, a1.x, a1.y, a1.z, a1.w};
            short8 h8, l8;
#pragma unroll
            for (int j = 0; j < 8; ++j) {
                short h = bf16_rne(av[j]);
                h8[j] = h;
                l8[j] = bf16_rne(av[j] - bf16_to_f(h));
            }
            char* dAh = smem + 32768 + (cur ^ 1) * 8192;
            *(short8*)(dAh + aslotb) = h8;
            *(short8*)(dAh + 4096 + aslotb) = l8;
        }
        __syncthreads();
    }

    // ---- phase 2a: acc1 + et_b -> ef_s [64][132] f32 @0 ----
    float* ef_s = (float*)smem;
#pragma unroll
    for (int c = 0; c < 2; ++c) {
        int col = wv * 32 + c * 16 + (lane & 15);
        float bias = et_b[col];
#pragma unroll
        for (int rt = 0; rt < 4; ++rt) {
#pragma unroll
            for (int q = 0; q < 4; ++q) {
                int row = rt * 16 + ((lane >> 4) << 2) + q;
                ef_s[row * 132 + col] = acc1[rt][c][q] + bias;
            }
        }
    }
    __syncthreads();

    // ---- phase 2b: ef_s -> A-fragments (hi/lo) @49152 ----
    short* AF = (short*)(smem + 49152);
#pragma unroll
    for (int u2 = 0; u2 < 4; ++u2) {
        int unit = t + u2 * 256;            // (kt2*4+rt)*64 + ln
        int kt2 = unit >> 8;
        int rt = (unit >> 6) & 3;
        int ln = unit & 63;
        int row = rt * 16 + (ln & 15);
        int feat0 = kt2 * 32 + (ln >> 4) * 8;
        const float* src = ef_s + row * 132 + feat0;
        float4 v0 = *(const float4*)(src);
        float4 v1 = *(const float4*)(src + 4);
        float av[8] = {v0.x, v0.y, v0.z, v0.w, v1.x, v1.y, v1.z, v1.w};
        short8 h8, l8;
#pragma unroll
        for (int j = 0; j < 8; ++j) {
            short hh = bf16_rne(av[j]);
            h8[j] = hh;
            l8[j] = bf16_rne(av[j] - bf16_to_f(hh));
        }
        *(short8*)(AF + (((kt2 * 2 + 0) * 4 + rt) * 64 + ln) * 8) = h8;
        *(short8*)(AF + (((kt2 * 2 + 1) * 4 + rt) * 64 + ln) * 8) = l8;
    }
    __syncthreads();

    // ---- phase 3: g = edge_f @ wih^T  (K=128, 4 kt, B staged @0) ----
    f32x4 acc[4][6] = {};
    for (int kt = 0; kt < 4; ++kt) {
        {
            const char* src = (const char*)Bf2 + (size_t)kt * 49152;
#pragma unroll
            for (int i = 0; i < 12; ++i) {
                int off = (t + i * 256) * 16;
                gload_lds16(src + off, smem + off);
            }
        }
        __syncthreads();

        const char* Ab = (const char*)AF + kt * 8192;
        short8 Ahf[4], Alf[4];
#pragma unroll
        for (int rt = 0; rt < 4; ++rt) {
            Ahf[rt] = *(const short8*)(Ab + (rt * 64 + lane) * 16);
            Alf[rt] = *(const short8*)(Ab + 4096 + (rt * 64 + lane) * 16);
        }
#pragma unroll
        for (int c = 0; c < 6; ++c) {
            int ctg = ((c >> 1) << 3) + (wv << 1) + (c & 1);
            short8 Bh = *(const short8*)(smem + (ctg * 64 + lane) * 16);
            short8 Bl = *(const short8*)(smem + 24576 + (ctg * 64 + lane) * 16);
#pragma unroll
            for (int rt = 0; rt < 4; ++rt) {
                acc[rt][c] = __builtin_amdgcn_mfma_f32_16x16x32_bf16(Ahf[rt], Bh, acc[rt][c], 0, 0, 0);
                acc[rt][c] = __builtin_amdgcn_mfma_f32_16x16x32_bf16(Alf[rt], Bh, acc[rt][c], 0, 0, 0);
                acc[rt][c] = __builtin_amdgcn_mfma_f32_16x16x32_bf16(Ahf[rt], Bl, acc[rt][c], 0, 0, 0);
            }
        }
        __syncthreads();
    }

    // ---- epilogue: GRU gates -> eh_s, softmax-pool (validated r3-r6) ----
    const int EHP = 132;
    float* eh_s = (float*)smem;                     // [64][132]
    float* red  = (float*)(smem + 33792);           // 256 f
    float* s2v  = red + 256;
    float* ewv  = s2v + 64;
#pragma unroll
    for (int cc = 0; cc < 2; ++cc) {
        int o = (wv << 5) + (cc << 4) + (lane & 15);
        float bco = bih[o] + bhh[o];
        float bcz = bih[128 + o] + bhh[128 + o];
        float bcn = bih[256 + o];
        float bn3 = bhh[256 + o];
#pragma unroll
        for (int rt = 0; rt < 4; ++rt) {
#pragma unroll
            for (int q = 0; q < 4; ++q) {
                int row = rt * 16 + ((lane >> 4) << 2) + q;
                float r = sigmoidf_(acc[rt][cc][q] + bco);
                float z = sigmoidf_(acc[rt][2 + cc][q] + bcz);
                float n = tanhf_(acc[rt][4 + cc][q] + bcn + r * bn3);
                eh_s[row * EHP + o] = (1.0f - z) * n;
            }
        }
    }
    __syncthreads();

    {
        int j = t >> 2, q = t & 3;
        const float* row = eh_s + j * EHP + q * 32;
        const float* wb = natt_w + 128 + q * 32;
        float a = 0.f;
#pragma unroll
        for (int k2 = 0; k2 < 32; ++k2) a = fmaf(row[k2], wb[k2], a);
        red[t] = a;
    }
    __syncthreads();
    if (t < 64) s2v[t] = red[4 * t] + red[4 * t + 1] + red[4 * t + 2] + red[4 * t + 3];
    __syncthreads();
    if (t < 64) {
        float m = -1e30f;
        for (int j = 0; j < 64; ++j) m = fmaxf(m, s2v[j]);
        ewv[t] = __expf(s2v[t] - m);
    }
    __syncthreads();
    float inv = 0.f;
    for (int j = 0; j < 64; ++j) inv += ewv[j];
    inv = 1.0f / inv;
    {
        int o = t & 127, h = t >> 7;
        float a = 0.f;
        for (int j = h * 32; j < h * 32 + 32; ++j)
            a = fmaf(ewv[j], eh_s[j * EHP + o], a);
        __syncthreads();
        red[t] = a;
    }
    __syncthreads();
    if (t < 128) {
        float v = (red[t] + red[t + 128]) * inv;
        nh_p[(size_t)g * 128 + t] = v;
        red[t] = v * eatt_w[t];
    }
    __syncthreads();
    for (int s = 64; s > 0; s >>= 1) {
        if (t < s) red[t] += red[t + s];
        __syncthreads();
    }
    if (t == 0) u_out[g] = red[0];
}

// -------- classifier input --------------------------------------------------
__global__ __launch_bounds__(128) void ci_kernel(
    const float* __restrict__ nh_p, const float* __restrict__ u,
    const int* __restrict__ pairs, float* __restrict__ ci)
{
    const int bp = blockIdx.x;
    const int b  = bp >> 7;
    const int t  = threadIdx.x;
    int i0 = pairs[bp * 2 + 0];
    int i1 = pairs[bp * 2 + 1];
    const float* n0 = nh_p + (size_t)(b * 64 + i0) * 128;
    const float* n1 = nh_p + (size_t)(b * 64 + i1) * 128;
    float s = sigmoidf_(u[b * 64 + i1] - u[b * 64 + i0]);
    float v0 = n0[t], v1 = n1[t];
    ci[(size_t)bp * 256 + t]       = 0.5f * (v0 + v1);
    ci[(size_t)bp * 256 + 128 + t] = s * v1 + (1.0f - s) * v0;
}

// -------- fused head: layer1 MFMA GEMM + ReLU + layer2 (w2 in LDS) ---------
__global__ __launch_bounds__(256, 1) void headcls_kernel(
    const float* __restrict__ ci,
    const short* __restrict__ Wf1_hi, const short* __restrict__ Wf1_lo,
    const float* __restrict__ b1a, const float* __restrict__ b1b,
    const float* __restrict__ b1c,
    const float* __restrict__ w2a, const float* __restrict__ w2b,
    const float* __restrict__ w2c,
    const float* __restrict__ b2a, const float* __restrict__ b2b,
    const float* __restrict__ b2c,
    float* __restrict__ out)
{
    __shared__ __align__(16) char smem[139264];
    const int t = threadIdx.x;
    const int wv = t >> 6, lane = t & 63;
    const int rb = blockIdx.x;
    const int hd = blockIdx.y;
    const float* b1 = hd == 0 ? b1a : hd == 1 ? b1b : b1c;
    const float* w2 = hd == 0 ? w2a : hd == 1 ? w2b : w2c;
    const float* b2 = hd == 0 ? b2a : hd == 1 ? b2b : b2c;
    const int od  = hd == 0 ? 6 : hd == 1 ? 5 : 3;
    const int off = hd == 0 ? 0 : hd == 1 ? 6 : 11;

    const int arow = t >> 2, akb = t & 3;
    const int abyte = ((((arow >> 4) * 64) + ((akb << 4) | (arow & 15))) * 8) * 2;
    const float* aptr = ci + ((size_t)rb * 32 + arow) * 256 + akb * 8;

    f32x4 acc[2][8] = {};

    float4 a0, a1;
    if (t < 128) {
        a0 = *(const float4*)(aptr);
        a1 = *(const float4*)(aptr + 4);
    }
    {
        const char* sh = (const char*)(Wf1_hi + (size_t)hd * 8 * 32 * 512);
        const char* sl = (const char*)(Wf1_lo + (size_t)hd * 8 * 32 * 512);
#pragma unroll
        for (int i = 0; i < 8; ++i) {
            int ch = i * 4 + wv;
            int o2 = ch * 1024 + lane * 16;
            gload_lds16(sh + o2, smem + ch * 1024);
            gload_lds16(sl + o2, smem + 32768 + ch * 1024);
        }
    }
    if (t < 128) {
        float av[8] = {a0.x, a0.y, a0.z, a0.w, a1.x, a1.y, a1.z, a1.w};
        short8 h8, l8;
#pragma unroll
        for (int j = 0; j < 8; ++j) {
            short h = bf16_rne(av[j]);
            h8[j] = h;
            l8[j] = bf16_rne(av[j] - bf16_to_f(h));
        }
        *(short8*)(smem + 131072 + abyte) = h8;
        *(short8*)(smem + 131072 + 2048 + abyte) = l8;
    }
    __syncthreads();

    for (int kt = 0; kt < 8; ++kt) {
        const int cur = kt & 1;
        const char* Bh_c = smem + cur * 65536;
        const char* Bl_c = Bh_c + 32768;
        const char* Ah_c = smem + 131072 + cur * 4096;
        const char* Al_c = Ah_c + 2048;

        float4 b0, b1v;
        if (kt < 7) {
            const char* sh = (const char*)(Wf1_hi + ((size_t)hd * 8 + kt + 1) * 32 * 512);
            const char* sl = (const char*)(Wf1_lo + ((size_t)hd * 8 + kt + 1) * 32 * 512);
            char* dBh = smem + (cur ^ 1) * 65536;
#pragma unroll
            for (int i = 0; i < 8; ++i) {
                int ch = i * 4 + wv;
                int o2 = ch * 1024 + lane * 16;
                gload_lds16(sh + o2, dBh + ch * 1024);
                gload_lds16(sl + o2, dBh + 32768 + ch * 1024);
            }
            if (t < 128) {
                b0  = *(const float4*)(aptr + (size_t)(kt + 1) * 32);
                b1v = *(const float4*)(aptr + (size_t)(kt + 1) * 32 + 4);
            }
        }

        short8 Ah[2], Al[2];
#pragma unroll
        for (int rt = 0; rt < 2; ++rt) {
            Ah[rt] = *(const short8*)(Ah_c + (rt * 64 + lane) * 16);
            Al[rt] = *(const short8*)(Al_c + (rt * 64 + lane) * 16);
        }
#pragma unroll
        for (int c = 0; c < 8; ++c) {
            int ctg = wv * 8 + c;
            short8 Bh = *(const short8*)(Bh_c + (ctg * 64 + lane) * 16);
            short8 Bl = *(const short8*)(Bl_c + (ctg * 64 + lane) * 16);
#pragma unroll
            for (int rt = 0; rt < 2; ++rt) {
                acc[rt][c] = __builtin_amdgcn_mfma_f32_16x16x32_bf16(Ah[rt], Bh, acc[rt][c], 0, 0, 0);
                acc[rt][c] = __builtin_amdgcn_mfma_f32_16x16x32_bf16(Al[rt], Bh, acc[rt][c], 0, 0, 0);
                acc[rt][c] = __builtin_amdgcn_mfma_f32_16x16x32_bf16(Ah[rt], Bl, acc[rt][c], 0, 0, 0);
            }
        }

        if (kt < 7 && t < 128) {
            float av[8] = {b0.x, b0.y, b0.z, b0.w, b1v.x, b1v.y, b1v.z, b1v.w};
            short8 h8, l8;
#pragma unroll
            for (int j = 0; j < 8; ++j) {
                short h = bf16_rne(av[j]);
                h8[j] = h;
                l8[j] = bf16_rne(av[j] - bf16_to_f(h));
            }
            char* dAh = smem + 131072 + (cur ^ 1) * 4096;
            *(short8*)(dAh + abyte) = h8;
            *(short8*)(dAh + 2048 + abyte) = l8;
        }
        __syncthreads();
    }

    // h_s [32][516] @0 ; w2_s @66048 (both overlay B bufs, post-sync)
    float* h_s  = (float*)smem;
    float* w2_s = (float*)(smem + 66048);
    for (int idx = t; idx < 512 * od; idx += 256) w2_s[idx] = w2[idx];
#pragma unroll
    for (int c = 0; c < 8; ++c) {
        int ctg = wv * 8 + c;
        int col = ctg * 16 + (lane & 15);
        float bias = b1[col];
#pragma unroll
        for (int rt = 0; rt < 2; ++rt) {
#pragma unroll
            for (int q = 0; q < 4; ++q) {
                int row = rt * 16 + ((lane >> 4) << 2) + q;
                h_s[row * 516 + col] = fmaxf(acc[rt][c][q] + bias, 0.f);
            }
        }
    }
    __syncthreads();

    {
        int row = t >> 3, o = t & 7;
        if (o < od) {
            const float* hr = h_s + row * 516;
            float a = b2[o];
            for (int c = 0; c < 512; ++c)
                a = fmaf(hr[c], w2_s[c * od + o], a);
            out[((size_t)rb * 32 + row) * 14 + off + o] = a;
        }
    }
}

// ---------------------------------------------------------------------------
extern "C" void kernel_launch(void* const* d_in, const int* in_sizes, int n_in,
                              void* d_out, int out_size, void* d_ws, size_t ws_size,
                              hipStream_t stream)
{
    const float* x_edge   = (const float*)d_in[1];
    const float* et_w     = (const float*)d_in[6];
    const float* et_b     = (const float*)d_in[7];
    const float* egru_wih = (const float*)d_in[11];
    const float* egru_bih = (const float*)d_in[12];
    const float* egru_bhh = (const float*)d_in[13];
    const float* natt_w   = (const float*)d_in[14];
    const float* eatt_w   = (const float*)d_in[16];
    const float* lr_w1 = (const float*)d_in[18];
    const float* lr_b1 = (const float*)d_in[19];
    const float* lr_w2 = (const float*)d_in[20];
    const float* lr_b2 = (const float*)d_in[21];
    const float* cr_w1 = (const float*)d_in[22];
    const float* cr_b1 = (const float*)d_in[23];
    const float* cr_w2 = (const float*)d_in[24];
    const float* cr_b2 = (const float*)d_in[25];
    const float* mr_w1 = (const float*)d_in[26];
    const float* mr_b1 = (const float*)d_in[27];
    const float* mr_w2 = (const float*)d_in[28];
    const float* mr_b2 = (const float*)d_in[29];
    const int* pairs   = (const int*)d_in[30];
    float* out = (float*)d_out;
    char* ws = (char*)d_ws;

    // workspace layout (bytes) — 4.66 MB total
    short* Bf1    = (short*)(ws + 0);          // 262144
    short* Bf2    = (short*)(ws + 262144);     // 196608
    short* Wf1_hi = (short*)(ws + 458752);     // 786432
    short* Wf1_lo = (short*)(ws + 1245184);    // 786432
    float* nh_p   = (float*)(ws + 2031616);    // 524288
    float* u      = (float*)(ws + 2555904);    // 4096
    float* ci     = (float*)(ws + 2560000);    // 2097152 -> end 4657152

    prep_all<<<1984, 256, 0, stream>>>(et_w, egru_wih, lr_w1, cr_w1, mr_w1,
                                       Bf1, Bf2, Wf1_hi, Wf1_lo);

    fused_kernel<<<1024, 256, 0, stream>>>(
        x_edge, Bf1, Bf2, et_b, egru_bih, egru_bhh, natt_w, eatt_w, nh_p, u);

    ci_kernel<<<2048, 128, 0, stream>>>(nh_p, u, pairs, ci);

    headcls_kernel<<<dim3(64, 3), 256, 0, stream>>>(
        ci, Wf1_hi, Wf1_lo, lr_b1, cr_b1, mr_b1,
        lr_w2, cr_w2, mr_w2, lr_b2, cr_b2, mr_b2, out);
}

// Round 8
// 93.328 us; speedup vs baseline: 2.0990x; 1.0813x over previous
//
#include <hip/hip_runtime.h>
#include <math.h>
#include <stdint.h>

// ---------------------------------------------------------------------------
// Algebraic reductions (verified, absmax 2.4e-4):
//  * 2-step loop idempotent -> run once; node branch cancels entirely.
//  * Factored GEMM (rank-128): edge_f = x_edge @ et_w (8.6 GF), then
//    g = edge_f @ wih^T (6.4 GF) — beats composed 25.8 GF.
//  * Fully fused: ef GEMM -> LDS transpose -> g GEMM -> gates+pool.
//  * Round-8: phase1 restructured to kill the per-kt vmcnt(0) drain:
//      - B (et_w frags) in REGISTERS (coalesced global, L2-warm, 1-deep pf)
//      - A 2-deep register prefetch -> convert -> LDS dbuf (only LDS user)
//      - barrier = inline "s_waitcnt lgkmcnt(0); s_barrier" (global loads
//        stay in flight across it; compiler counted-waits cover reg uses)
//  * Precision: split-bf16 (hi+lo) 3-term MFMA ~= f32 accuracy.
// ---------------------------------------------------------------------------

typedef __attribute__((ext_vector_type(8))) short short8;
typedef __attribute__((ext_vector_type(4))) float f32x4;

#define DEVINL __device__ __forceinline__

DEVINL float sigmoidf_(float x) { return 1.0f / (1.0f + __expf(-x)); }
DEVINL float tanhf_(float x) {
    float e = __expf(2.0f * x);
    return (e - 1.0f) / (e + 1.0f);
}
DEVINL short bf16_rne(float f) {
    uint32_t u = __float_as_uint(f);
    u += 0x7FFFu + ((u >> 16) & 1u);
    return (short)(u >> 16);
}
DEVINL float bf16_to_f(short s) {
    return __uint_as_float(((uint32_t)(uint16_t)s) << 16);
}
DEVINL void gload_lds16(const void* g, void* l) {
    __builtin_amdgcn_global_load_lds(
        (const __attribute__((address_space(1))) void*)(uintptr_t)g,
        (__attribute__((address_space(3))) void*)(uint32_t)(uintptr_t)l,
        16, 0, 0);
}
// LDS-only barrier: does NOT drain vmcnt (in-flight global prefetch survives)
DEVINL void ldsbar() {
    asm volatile("s_waitcnt lgkmcnt(0)\n\ts_barrier" ::: "memory");
    __builtin_amdgcn_sched_barrier(0);
}

// ---------------- prep: all weight fragment packing in one kernel ----------
// B-fragment convention (validated r3-r7): col n = ct*16+(l&15),
// k = kt*32 + ((l>>4)&3)*8 + j.
// bid <256   : et_w [512,128] -> Bf1 [kt16][pl2][ct8][lane][j]
// bid 256-447: wih  [384,128] -> Bf2 [kt4][pl2][ct24][lane][j]
// bid >=448  : heads W1 (3x[256,512]) -> Wf1_hi/lo [h][kt8][ct32][lane][j]
__global__ __launch_bounds__(256) void prep_all(
    const float* __restrict__ et_w, const float* __restrict__ wih,
    const float* __restrict__ w1a, const float* __restrict__ w1b,
    const float* __restrict__ w1c,
    short* __restrict__ Bf1, short* __restrict__ Bf2,
    short* __restrict__ Wf1_hi, short* __restrict__ Wf1_lo)
{
    const int bid = blockIdx.x, t = threadIdx.x;
    if (bid < 256) {
        int idx = bid * 256 + t;            // [0,65536)
        int k = idx >> 7, n = idx & 127;
        float v = et_w[(size_t)k * 128 + n];
        short hi = bf16_rne(v), lo = bf16_rne(v - bf16_to_f(hi));
        int kt = k >> 5, ct = n >> 4;
        int lane = (((k >> 3) & 3) << 4) | (n & 15);
        int j = k & 7;
        size_t s0 = ((((size_t)kt * 2 + 0) * 8 + ct) * 64 + lane) * 8 + j;
        size_t s1 = ((((size_t)kt * 2 + 1) * 8 + ct) * 64 + lane) * 8 + j;
        Bf1[s0] = hi; Bf1[s1] = lo;
    } else if (bid < 448) {
        int idx = (bid - 256) * 256 + t;    // [0,49152)
        int n = idx >> 7, k = idx & 127;
        float v = wih[(size_t)n * 128 + k];
        short hi = bf16_rne(v), lo = bf16_rne(v - bf16_to_f(hi));
        int kt = k >> 5, ct = n >> 4;
        int lane = (((k >> 3) & 3) << 4) | (n & 15);
        int j = k & 7;
        size_t s0 = ((((size_t)kt * 2 + 0) * 24 + ct) * 64 + lane) * 8 + j;
        size_t s1 = ((((size_t)kt * 2 + 1) * 24 + ct) * 64 + lane) * 8 + j;
        Bf2[s0] = hi; Bf2[s1] = lo;
    } else {
        int idx = (bid - 448) * 256 + t;    // [0,393216)
        int h = idx >> 17;
        int r = idx & 131071;
        int k = r >> 9, c = r & 511;
        const float* w1 = (h == 0) ? w1a : (h == 1) ? w1b : w1c;
        float v = w1[(size_t)k * 512 + c];
        short hi = bf16_rne(v), lo = bf16_rne(v - bf16_to_f(hi));
        int kt = k >> 5, ct = c >> 4;
        int lane = (((k >> 3) & 3) << 4) | (c & 15);
        int j = k & 7;
        size_t fidx = ((((size_t)h * 8 + kt) * 32 + ct) * 64 + lane) * 8 + j;
        Wf1_hi[fidx] = hi;
        Wf1_lo[fidx] = lo;
    }
}

// one phase-1 iteration. BH*/BL* = current B regs; NB* = next-B regs (load
// kt+1); PCV* = A regs holding A(kt+1) to convert+ds_write; PLD* = A regs to
// refill with A(kt+2); RBUF/WBUF = LDS byte offsets of read/write A buffers.
#define PH1_ITER(KT, BH0, BH1, BL0, BL1, NBH0, NBH1, NBL0, NBL1,              \
                 PCV0, PCV1, PLD0, PLD1, RBUF, WBUF)                          \
    {                                                                         \
        if ((KT) < 15) {                                                      \
            const short* bkt = Bf1 + (size_t)((KT) + 1) * 8192;               \
            NBH0 = *(const short8*)(bkt + ct0 * 512 + ln8);                   \
            NBH1 = *(const short8*)(bkt + ct1 * 512 + ln8);                   \
            NBL0 = *(const short8*)(bkt + 4096 + ct0 * 512 + ln8);            \
            NBL1 = *(const short8*)(bkt + 4096 + ct1 * 512 + ln8);            \
            float av[8] = {PCV0.x, PCV0.y, PCV0.z, PCV0.w,                    \
                           PCV1.x, PCV1.y, PCV1.z, PCV1.w};                   \
            short8 h8, l8;                                                    \
            _Pragma("unroll") for (int j = 0; j < 8; ++j) {                   \
                short h = bf16_rne(av[j]);                                    \
                h8[j] = h;                                                    \
                l8[j] = bf16_rne(av[j] - bf16_to_f(h));                       \
            }                                                                 \
            *(short8*)(smem + (WBUF) + aslotb) = h8;                          \
            *(short8*)(smem + (WBUF) + 4096 + aslotb) = l8;                   \
        }                                                                     \
        if ((KT) < 14) {                                                      \
            PLD0 = *(const float4*)(aptr + (size_t)((KT) + 2) * 32);          \
            PLD1 = *(const float4*)(aptr + (size_t)((KT) + 2) * 32 + 4);      \
        }                                                                     \
        {                                                                     \
            const char* Ah_c = smem + (RBUF);                                 \
            short8 Ahf[4], Alf[4];                                            \
            _Pragma("unroll") for (int rt = 0; rt < 4; ++rt) {                \
                Ahf[rt] = *(const short8*)(Ah_c + (rt * 64 + lane) * 16);     \
                Alf[rt] = *(const short8*)(Ah_c + 4096 + (rt * 64 + lane) * 16); \
            }                                                                 \
            _Pragma("unroll") for (int rt = 0; rt < 4; ++rt) {                \
                acc1[rt][0] = __builtin_amdgcn_mfma_f32_16x16x32_bf16(Ahf[rt], BH0, acc1[rt][0], 0, 0, 0); \
                acc1[rt][0] = __builtin_amdgcn_mfma_f32_16x16x32_bf16(Alf[rt], BH0, acc1[rt][0], 0, 0, 0); \
                acc1[rt][0] = __builtin_amdgcn_mfma_f32_16x16x32_bf16(Ahf[rt], BL0, acc1[rt][0], 0, 0, 0); \
                acc1[rt][1] = __builtin_amdgcn_mfma_f32_16x16x32_bf16(Ahf[rt], BH1, acc1[rt][1], 0, 0, 0); \
                acc1[rt][1] = __builtin_amdgcn_mfma_f32_16x16x32_bf16(Alf[rt], BH1, acc1[rt][1], 0, 0, 0); \
                acc1[rt][1] = __builtin_amdgcn_mfma_f32_16x16x32_bf16(Ahf[rt], BL1, acc1[rt][1], 0, 0, 0); \
            }                                                                 \
        }                                                                     \
        ldsbar();                                                             \
    }

// ---------------- fused: ef GEMM -> transpose -> g GEMM -> gates+pool ------
// Block = one (b,i) group (64 rows). 256 thr, 4 waves.
// LDS map (80 KB total, 2 blocks/CU):
//  phase1: A dbuf 2*8KB @0..16384 (ONLY LDS use; B lives in registers)
//  phase2: ef_s [64][132] f32 @0 (overlay); AF (A-frags) 32KB @49152
//  phase3: Bf2 tile 48KB @0 (overlay); AF @49152 persists
//  epilogue: eh_s [64][132] @0 + red/s2v/ewv @33792
__global__ __launch_bounds__(256, 2) void fused_kernel(
    const float* __restrict__ x_edge,
    const short* __restrict__ Bf1, const short* __restrict__ Bf2,
    const float* __restrict__ et_b,
    const float* __restrict__ bih, const float* __restrict__ bhh,
    const float* __restrict__ natt_w, const float* __restrict__ eatt_w,
    float* __restrict__ nh_p, float* __restrict__ u_out)
{
    __shared__ __align__(16) char smem[81920];
    const int t = threadIdx.x;
    const int wv = t >> 6, lane = t & 63;
    const int g = blockIdx.x;
    const size_t bm = (size_t)g * 64;

    const int arow = t >> 2, akb = t & 3;
    const int aslotb = (((arow >> 4) * 64) + ((akb << 4) | (arow & 15))) * 16;
    const float* aptr = x_edge + (bm + arow) * 512 + akb * 8;

    const int ct0 = wv * 2, ct1 = wv * 2 + 1;
    const int ln8 = lane * 8;

    f32x4 acc1[4][2] = {};

    // phase-1 registers: A 2-deep (slotA = even kt, slotB = odd kt), B dbuf
    float4 paA0, paA1, paB0, paB1;
    short8 bhA0, bhA1, blA0, blA1, bhB0, bhB1, blB0, blB1;

    // ---- prologue: A(0),A(1) -> regs; B(0) -> regs; A(0) -> LDS buf0 ----
    paA0 = *(const float4*)(aptr);
    paA1 = *(const float4*)(aptr + 4);
    paB0 = *(const float4*)(aptr + 32);
    paB1 = *(const float4*)(aptr + 36);
    {
        const short* bkt = Bf1;
        bhA0 = *(const short8*)(bkt + ct0 * 512 + ln8);
        bhA1 = *(const short8*)(bkt + ct1 * 512 + ln8);
        blA0 = *(const short8*)(bkt + 4096 + ct0 * 512 + ln8);
        blA1 = *(const short8*)(bkt + 4096 + ct1 * 512 + ln8);
    }
    {
        float av[8] = {paA0.x, paA0.y, paA0.z, paA0.w,
                       paA1.x, paA1.y, paA1.z, paA1.w};
        short8 h8, l8;
#pragma unroll
        for (int j = 0; j < 8; ++j) {
            short h = bf16_rne(av[j]);
            h8[j] = h;
            l8[j] = bf16_rne(av[j] - bf16_to_f(h));
        }
        *(short8*)(smem + aslotb) = h8;
        *(short8*)(smem + 4096 + aslotb) = l8;
    }
    ldsbar();

    // ---- main loop: 16 kt, lgkm-only barrier, global prefetch in flight ---
    for (int kt = 0; kt < 16; kt += 2) {
        PH1_ITER(kt, bhA0, bhA1, blA0, blA1, bhB0, bhB1, blB0, blB1,
                 paB0, paB1, paA0, paA1, 0, 8192)
        PH1_ITER(kt + 1, bhB0, bhB1, blB0, blB1, bhA0, bhA1, blA0, blA1,
                 paA0, paA1, paB0, paB1, 8192, 0)
    }
    __syncthreads();

    // ---- phase 2a: acc1 + et_b -> ef_s [64][132] f32 @0 ----
    float* ef_s = (float*)smem;
#pragma unroll
    for (int c = 0; c < 2; ++c) {
        int col = wv * 32 + c * 16 + (lane & 15);
        float bias = et_b[col];
#pragma unroll
        for (int rt = 0; rt < 4; ++rt) {
#pragma unroll
            for (int q = 0; q < 4; ++q) {
                int row = rt * 16 + ((lane >> 4) << 2) + q;
                ef_s[row * 132 + col] = acc1[rt][c][q] + bias;
            }
        }
    }
    __syncthreads();

    // ---- phase 2b: ef_s -> A-fragments (hi/lo) @49152 ----
    short* AF = (short*)(smem + 49152);
#pragma unroll
    for (int u2 = 0; u2 < 4; ++u2) {
        int unit = t + u2 * 256;            // (kt2*4+rt)*64 + ln
        int kt2 = unit >> 8;
        int rt = (unit >> 6) & 3;
        int ln = unit & 63;
        int row = rt * 16 + (ln & 15);
        int feat0 = kt2 * 32 + (ln >> 4) * 8;
        const float* src = ef_s + row * 132 + feat0;
        float4 v0 = *(const float4*)(src);
        float4 v1 = *(const float4*)(src + 4);
        float av[8] = {v0.x, v0.y, v0.z, v0.w, v1.x, v1.y, v1.z, v1.w};
        short8 h8, l8;
#pragma unroll
        for (int j = 0; j < 8; ++j) {
            short hh = bf16_rne(av[j]);
            h8[j] = hh;
            l8[j] = bf16_rne(av[j] - bf16_to_f(hh));
        }
        *(short8*)(AF + (((kt2 * 2 + 0) * 4 + rt) * 64 + ln) * 8) = h8;
        *(short8*)(AF + (((kt2 * 2 + 1) * 4 + rt) * 64 + ln) * 8) = l8;
    }
    __syncthreads();

    // ---- phase 3: g = edge_f @ wih^T  (K=128, 4 kt, B staged @0) ----
    f32x4 acc[4][6] = {};
    for (int kt = 0; kt < 4; ++kt) {
        {
            const char* src = (const char*)Bf2 + (size_t)kt * 49152;
#pragma unroll
            for (int i = 0; i < 12; ++i) {
                int off = (t + i * 256) * 16;
                gload_lds16(src + off, smem + off);
            }
        }
        __syncthreads();

        const char* Ab = (const char*)AF + kt * 8192;
        short8 Ahf[4], Alf[4];
#pragma unroll
        for (int rt = 0; rt < 4; ++rt) {
            Ahf[rt] = *(const short8*)(Ab + (rt * 64 + lane) * 16);
            Alf[rt] = *(const short8*)(Ab + 4096 + (rt * 64 + lane) * 16);
        }
#pragma unroll
        for (int c = 0; c < 6; ++c) {
            int ctg = ((c >> 1) << 3) + (wv << 1) + (c & 1);
            short8 Bh = *(const short8*)(smem + (ctg * 64 + lane) * 16);
            short8 Bl = *(const short8*)(smem + 24576 + (ctg * 64 + lane) * 16);
#pragma unroll
            for (int rt = 0; rt < 4; ++rt) {
                acc[rt][c] = __builtin_amdgcn_mfma_f32_16x16x32_bf16(Ahf[rt], Bh, acc[rt][c], 0, 0, 0);
                acc[rt][c] = __builtin_amdgcn_mfma_f32_16x16x32_bf16(Alf[rt], Bh, acc[rt][c], 0, 0, 0);
                acc[rt][c] = __builtin_amdgcn_mfma_f32_16x16x32_bf16(Ahf[rt], Bl, acc[rt][c], 0, 0, 0);
            }
        }
        __syncthreads();
    }

    // ---- epilogue: GRU gates -> eh_s, softmax-pool (validated r3-r7) ----
    const int EHP = 132;
    float* eh_s = (float*)smem;                     // [64][132]
    float* red  = (float*)(smem + 33792);           // 256 f
    float* s2v  = red + 256;
    float* ewv  = s2v + 64;
#pragma unroll
    for (int cc = 0; cc < 2; ++cc) {
        int o = (wv << 5) + (cc << 4) + (lane & 15);
        float bco = bih[o] + bhh[o];
        float bcz = bih[128 + o] + bhh[128 + o];
        float bcn = bih[256 + o];
        float bn3 = bhh[256 + o];
#pragma unroll
        for (int rt = 0; rt < 4; ++rt) {
#pragma unroll
            for (int q = 0; q < 4; ++q) {
                int row = rt * 16 + ((lane >> 4) << 2) + q;
                float r = sigmoidf_(acc[rt][cc][q] + bco);
                float z = sigmoidf_(acc[rt][2 + cc][q] + bcz);
                float n = tanhf_(acc[rt][4 + cc][q] + bcn + r * bn3);
                eh_s[row * EHP + o] = (1.0f - z) * n;
            }
        }
    }
    __syncthreads();

    {
        int j = t >> 2, q = t & 3;
        const float* row = eh_s + j * EHP + q * 32;
        const float* wb = natt_w + 128 + q * 32;
        float a = 0.f;
#pragma unroll
        for (int k2 = 0; k2 < 32; ++k2) a = fmaf(row[k2], wb[k2], a);
        red[t] = a;
    }
    __syncthreads();
    if (t < 64) s2v[t] = red[4 * t] + red[4 * t + 1] + red[4 * t + 2] + red[4 * t + 3];
    __syncthreads();
    if (t < 64) {
        float m = -1e30f;
        for (int j = 0; j < 64; ++j) m = fmaxf(m, s2v[j]);
        ewv[t] = __expf(s2v[t] - m);
    }
    __syncthreads();
    float inv = 0.f;
    for (int j = 0; j < 64; ++j) inv += ewv[j];
    inv = 1.0f / inv;
    {
        int o = t & 127, h = t >> 7;
        float a = 0.f;
        for (int j = h * 32; j < h * 32 + 32; ++j)
            a = fmaf(ewv[j], eh_s[j * EHP + o], a);
        __syncthreads();
        red[t] = a;
    }
    __syncthreads();
    if (t < 128) {
        float v = (red[t] + red[t + 128]) * inv;
        nh_p[(size_t)g * 128 + t] = v;
        red[t] = v * eatt_w[t];
    }
    __syncthreads();
    for (int s = 64; s > 0; s >>= 1) {
        if (t < s) red[t] += red[t + s];
        __syncthreads();
    }
    if (t == 0) u_out[g] = red[0];
}

// -------- classifier input --------------------------------------------------
__global__ __launch_bounds__(128) void ci_kernel(
    const float* __restrict__ nh_p, const float* __restrict__ u,
    const int* __restrict__ pairs, float* __restrict__ ci)
{
    const int bp = blockIdx.x;
    const int b  = bp >> 7;
    const int t  = threadIdx.x;
    int i0 = pairs[bp * 2 + 0];
    int i1 = pairs[bp * 2 + 1];
    const float* n0 = nh_p + (size_t)(b * 64 + i0) * 128;
    const float* n1 = nh_p + (size_t)(b * 64 + i1) * 128;
    float s = sigmoidf_(u[b * 64 + i1] - u[b * 64 + i0]);
    float v0 = n0[t], v1 = n1[t];
    ci[(size_t)bp * 256 + t]       = 0.5f * (v0 + v1);
    ci[(size_t)bp * 256 + 128 + t] = s * v1 + (1.0f - s) * v0;
}

// -------- fused head: layer1 MFMA GEMM + ReLU + layer2 (w2 in LDS) ---------
__global__ __launch_bounds__(256, 1) void headcls_kernel(
    const float* __restrict__ ci,
    const short* __restrict__ Wf1_hi, const short* __restrict__ Wf1_lo,
    const float* __restrict__ b1a, const float* __restrict__ b1b,
    const float* __restrict__ b1c,
    const float* __restrict__ w2a, const float* __restrict__ w2b,
    const float* __restrict__ w2c,
    const float* __restrict__ b2a, const float* __restrict__ b2b,
    const float* __restrict__ b2c,
    float* __restrict__ out)
{
    __shared__ __align__(16) char smem[139264];
    const int t = threadIdx.x;
    const int wv = t >> 6, lane = t & 63;
    const int rb = blockIdx.x;
    const int hd = blockIdx.y;
    const float* b1 = hd == 0 ? b1a : hd == 1 ? b1b : b1c;
    const float* w2 = hd == 0 ? w2a : hd == 1 ? w2b : w2c;
    const float* b2 = hd == 0 ? b2a : hd == 1 ? b2b : b2c;
    const int od  = hd == 0 ? 6 : hd == 1 ? 5 : 3;
    const int off = hd == 0 ? 0 : hd == 1 ? 6 : 11;

    const int arow = t >> 2, akb = t & 3;
    const int abyte = ((((arow >> 4) * 64) + ((akb << 4) | (arow & 15))) * 8) * 2;
    const float* aptr = ci + ((size_t)rb * 32 + arow) * 256 + akb * 8;

    f32x4 acc[2][8] = {};

    float4 a0, a1;
    if (t < 128) {
        a0 = *(const float4*)(aptr);
        a1 = *(const float4*)(aptr + 4);
    }
    {
        const char* sh = (const char*)(Wf1_hi + (size_t)hd * 8 * 32 * 512);
        const char* sl = (const char*)(Wf1_lo + (size_t)hd * 8 * 32 * 512);
#pragma unroll
        for (int i = 0; i < 8; ++i) {
            int ch = i * 4 + wv;
            int o2 = ch * 1024 + lane * 16;
            gload_lds16(sh + o2, smem + ch * 1024);
            gload_lds16(sl + o2, smem + 32768 + ch * 1024);
        }
    }
    if (t < 128) {
        float av[8] = {a0.x, a0.y, a0.z, a0.w, a1.x, a1.y, a1.z, a1.w};
        short8 h8, l8;
#pragma unroll
        for (int j = 0; j < 8; ++j) {
            short h = bf16_rne(av[j]);
            h8[j] = h;
            l8[j] = bf16_rne(av[j] - bf16_to_f(h));
        }
        *(short8*)(smem + 131072 + abyte) = h8;
        *(short8*)(smem + 131072 + 2048 + abyte) = l8;
    }
    __syncthreads();

    for (int kt = 0; kt < 8; ++kt) {
        const int cur = kt & 1;
        const char* Bh_c = smem + cur * 65536;
        const char* Bl_c = Bh_c + 32768;
        const char* Ah_c = smem + 131072 + cur * 4096;
        const char* Al_c = Ah_c + 2048;

        float4 b0, b1v;
        if (kt < 7) {
            const char* sh = (const char*)(Wf1_hi + ((size_t)hd * 8 + kt + 1) * 32 * 512);
            const char* sl = (const char*)(Wf1_lo + ((size_t)hd * 8 + kt + 1) * 32 * 512);
            char* dBh = smem + (cur ^ 1) * 65536;
#pragma unroll
            for (int i = 0; i < 8; ++i) {
                int ch = i * 4 + wv;
                int o2 = ch * 1024 + lane * 16;
                gload_lds16(sh + o2, dBh + ch * 1024);
                gload_lds16(sl + o2, dBh + 32768 + ch * 1024);
            }
            if (t < 128) {
                b0  = *(const float4*)(aptr + (size_t)(kt + 1) * 32);
                b1v = *(const float4*)(aptr + (size_t)(kt + 1) * 32 + 4);
            }
        }

        short8 Ah[2], Al[2];
#pragma unroll
        for (int rt = 0; rt < 2; ++rt) {
            Ah[rt] = *(const short8*)(Ah_c + (rt * 64 + lane) * 16);
            Al[rt] = *(const short8*)(Al_c + (rt * 64 + lane) * 16);
        }
#pragma unroll
        for (int c = 0; c < 8; ++c) {
            int ctg = wv * 8 + c;
            short8 Bh = *(const short8*)(Bh_c + (ctg * 64 + lane) * 16);
            short8 Bl = *(const short8*)(Bl_c + (ctg * 64 + lane) * 16);
#pragma unroll
            for (int rt = 0; rt < 2; ++rt) {
                acc[rt][c] = __builtin_amdgcn_mfma_f32_16x16x32_bf16(Ah[rt], Bh, acc[rt][c], 0, 0, 0);
                acc[rt][c] = __builtin_amdgcn_mfma_f32_16x16x32_bf16(Al[rt], Bh, acc[rt][c], 0, 0, 0);
                acc[rt][c] = __builtin_amdgcn_mfma_f32_16x16x32_bf16(Ah[rt], Bl, acc[rt][c], 0, 0, 0);
            }
        }

        if (kt < 7 && t < 128) {
            float av[8] = {b0.x, b0.y, b0.z, b0.w, b1v.x, b1v.y, b1v.z, b1v.w};
            short8 h8, l8;
#pragma unroll
            for (int j = 0; j < 8; ++j) {
                short h = bf16_rne(av[j]);
                h8[j] = h;
                l8[j] = bf16_rne(av[j] - bf16_to_f(h));
            }
            char* dAh = smem + 131072 + (cur ^ 1) * 4096;
            *(short8*)(dAh + abyte) = h8;
            *(short8*)(dAh + 2048 + abyte) = l8;
        }
        __syncthreads();
    }

    // h_s [32][516] @0 ; w2_s @66048 (both overlay B bufs, post-sync)
    float* h_s  = (float*)smem;
    float* w2_s = (float*)(smem + 66048);
    for (int idx = t; idx < 512 * od; idx += 256) w2_s[idx] = w2[idx];
#pragma unroll
    for (int c = 0; c < 8; ++c) {
        int ctg = wv * 8 + c;
        int col = ctg * 16 + (lane & 15);
        float bias = b1[col];
#pragma unroll
        for (int rt = 0; rt < 2; ++rt) {
#pragma unroll
            for (int q = 0; q < 4; ++q) {
                int row = rt * 16 + ((lane >> 4) << 2) + q;
                h_s[row * 516 + col] = fmaxf(acc[rt][c][q] + bias, 0.f);
            }
        }
    }
    __syncthreads();

    {
        int row = t >> 3, o = t & 7;
        if (o < od) {
            const float* hr = h_s + row * 516;
            float a = b2[o];
            for (int c = 0; c < 512; ++c)
                a = fmaf(hr[c], w2_s[c * od + o], a);
            out[((size_t)rb * 32 + row) * 14 + off + o] = a;
        }
    }
}

// ---------------------------------------------------------------------------
extern "C" void kernel_launch(void* const* d_in, const int* in_sizes, int n_in,
                              void* d_out, int out_size, void* d_ws, size_t ws_size,
                              hipStream_t stream)
{
    const float* x_edge   = (const float*)d_in[1];
    const float* et_w     = (const float*)d_in[6];
    const float* et_b     = (const float*)d_in[7];
    const float* egru_wih = (const float*)d_in[11];
    const float* egru_bih = (const float*)d_in[12];
    const float* egru_bhh = (const float*)d_in[13];
    const float* natt_w   = (const float*)d_in[14];
    const float* eatt_w   = (const float*)d_in[16];
    const float* lr_w1 = (const float*)d_in[18];
    const float* lr_b1 = (const float*)d_in[19];
    const float* lr_w2 = (const float*)d_in[20];
    const float* lr_b2 = (const float*)d_in[21];
    const float* cr_w1 = (const float*)d_in[22];
    const float* cr_b1 = (const float*)d_in[23];
    const float* cr_w2 = (const float*)d_in[24];
    const float* cr_b2 = (const float*)d_in[25];
    const float* mr_w1 = (const float*)d_in[26];
    const float* mr_b1 = (const float*)d_in[27];
    const float* mr_w2 = (const float*)d_in[28];
    const float* mr_b2 = (const float*)d_in[29];
    const int* pairs   = (const int*)d_in[30];
    float* out = (float*)d_out;
    char* ws = (char*)d_ws;

    // workspace layout (bytes) — 4.66 MB total
    short* Bf1    = (short*)(ws + 0);          // 262144
    short* Bf2    = (short*)(ws + 262144);     // 196608
    short* Wf1_hi = (short*)(ws + 458752);     // 786432
    short* Wf1_lo = (short*)(ws + 1245184);    // 786432
    float* nh_p   = (float*)(ws + 2031616);    // 524288
    float* u      = (float*)(ws + 2555904);    // 4096
    float* ci     = (float*)(ws + 2560000);    // 2097152 -> end 4657152

    prep_all<<<1984, 256, 0, stream>>>(et_w, egru_wih, lr_w1, cr_w1, mr_w1,
                                       Bf1, Bf2, Wf1_hi, Wf1_lo);

    fused_kernel<<<1024, 256, 0, stream>>>(
        x_edge, Bf1, Bf2, et_b, egru_bih, egru_bhh, natt_w, eatt_w, nh_p, u);

    ci_kernel<<<2048, 128, 0, stream>>>(nh_p, u, pairs, ci);

    headcls_kernel<<<dim3(64, 3), 256, 0, stream>>>(
        ci, Wf1_hi, Wf1_lo, lr_b1, cr_b1, mr_b1,
        lr_w2, cr_w2, mr_w2, lr_b2, cr_b2, mr_b2, out);
}

// Round 9
// 92.404 us; speedup vs baseline: 2.1200x; 1.0100x over previous
//
#include <hip/hip_runtime.h>
#include <math.h>
#include <stdint.h>

// ---------------------------------------------------------------------------
// Algebraic reductions (verified, absmax 2.4e-4):
//  * 2-step loop idempotent -> run once; node branch cancels entirely.
//  * Factored GEMM (rank-128): edge_f = x_edge @ et_w (8.6 GF), then
//    g = edge_f @ wih^T (6.4 GF) — beats composed 25.8 GF.
//  * Fully fused: ef GEMM -> LDS transpose -> g GEMM -> gates+pool.
//  * Round-9: occupancy 2->3 blocks/CU (the r5-r8 invariant bottleneck):
//      - LDS 80->48.5 KB: phase-2 transpose in two 32-row half-passes
//      - phase-3 B operands in REGISTERS (Bh-pass then Bl-pass), no LDS
//        staging, no barriers in phase 3
//      - __launch_bounds__(256,3) caps VGPR at ~170
//  * Precision: split-bf16 (hi+lo) 3-term MFMA ~= f32 accuracy.
// ---------------------------------------------------------------------------

typedef __attribute__((ext_vector_type(8))) short short8;
typedef __attribute__((ext_vector_type(4))) float f32x4;

#define DEVINL __device__ __forceinline__

DEVINL float sigmoidf_(float x) { return 1.0f / (1.0f + __expf(-x)); }
DEVINL float tanhf_(float x) {
    float e = __expf(2.0f * x);
    return (e - 1.0f) / (e + 1.0f);
}
DEVINL short bf16_rne(float f) {
    uint32_t u = __float_as_uint(f);
    u += 0x7FFFu + ((u >> 16) & 1u);
    return (short)(u >> 16);
}
DEVINL float bf16_to_f(short s) {
    return __uint_as_float(((uint32_t)(uint16_t)s) << 16);
}
DEVINL void gload_lds16(const void* g, void* l) {
    __builtin_amdgcn_global_load_lds(
        (const __attribute__((address_space(1))) void*)(uintptr_t)g,
        (__attribute__((address_space(3))) void*)(uint32_t)(uintptr_t)l,
        16, 0, 0);
}
// LDS-only barrier: does NOT drain vmcnt (in-flight global prefetch survives)
DEVINL void ldsbar() {
    asm volatile("s_waitcnt lgkmcnt(0)\n\ts_barrier" ::: "memory");
    __builtin_amdgcn_sched_barrier(0);
}

// ---------------- prep: all weight fragment packing in one kernel ----------
// B-fragment convention (validated r3-r8): col n = ct*16+(l&15),
// k = kt*32 + ((l>>4)&3)*8 + j.
// bid <256   : et_w [512,128] -> Bf1 [kt16][pl2][ct8][lane][j]
// bid 256-447: wih  [384,128] -> Bf2 [kt4][pl2][ct24][lane][j]
// bid >=448  : heads W1 (3x[256,512]) -> Wf1_hi/lo [h][kt8][ct32][lane][j]
__global__ __launch_bounds__(256) void prep_all(
    const float* __restrict__ et_w, const float* __restrict__ wih,
    const float* __restrict__ w1a, const float* __restrict__ w1b,
    const float* __restrict__ w1c,
    short* __restrict__ Bf1, short* __restrict__ Bf2,
    short* __restrict__ Wf1_hi, short* __restrict__ Wf1_lo)
{
    const int bid = blockIdx.x, t = threadIdx.x;
    if (bid < 256) {
        int idx = bid * 256 + t;            // [0,65536)
        int k = idx >> 7, n = idx & 127;
        float v = et_w[(size_t)k * 128 + n];
        short hi = bf16_rne(v), lo = bf16_rne(v - bf16_to_f(hi));
        int kt = k >> 5, ct = n >> 4;
        int lane = (((k >> 3) & 3) << 4) | (n & 15);
        int j = k & 7;
        size_t s0 = ((((size_t)kt * 2 + 0) * 8 + ct) * 64 + lane) * 8 + j;
        size_t s1 = ((((size_t)kt * 2 + 1) * 8 + ct) * 64 + lane) * 8 + j;
        Bf1[s0] = hi; Bf1[s1] = lo;
    } else if (bid < 448) {
        int idx = (bid - 256) * 256 + t;    // [0,49152)
        int n = idx >> 7, k = idx & 127;
        float v = wih[(size_t)n * 128 + k];
        short hi = bf16_rne(v), lo = bf16_rne(v - bf16_to_f(hi));
        int kt = k >> 5, ct = n >> 4;
        int lane = (((k >> 3) & 3) << 4) | (n & 15);
        int j = k & 7;
        size_t s0 = ((((size_t)kt * 2 + 0) * 24 + ct) * 64 + lane) * 8 + j;
        size_t s1 = ((((size_t)kt * 2 + 1) * 24 + ct) * 64 + lane) * 8 + j;
        Bf2[s0] = hi; Bf2[s1] = lo;
    } else {
        int idx = (bid - 448) * 256 + t;    // [0,393216)
        int h = idx >> 17;
        int r = idx & 131071;
        int k = r >> 9, c = r & 511;
        const float* w1 = (h == 0) ? w1a : (h == 1) ? w1b : w1c;
        float v = w1[(size_t)k * 512 + c];
        short hi = bf16_rne(v), lo = bf16_rne(v - bf16_to_f(hi));
        int kt = k >> 5, ct = c >> 4;
        int lane = (((k >> 3) & 3) << 4) | (c & 15);
        int j = k & 7;
        size_t fidx = ((((size_t)h * 8 + kt) * 32 + ct) * 64 + lane) * 8 + j;
        Wf1_hi[fidx] = hi;
        Wf1_lo[fidx] = lo;
    }
}

// one phase-1 iteration (validated r8). BH*/BL* = current B regs; NB* = next-B
// regs (load kt+1); PCV* = A regs holding A(kt+1) to convert+ds_write; PLD* =
// A regs to refill with A(kt+2); RBUF/WBUF = LDS offsets of A read/write bufs.
#define PH1_ITER(KT, BH0, BH1, BL0, BL1, NBH0, NBH1, NBL0, NBL1,              \
                 PCV0, PCV1, PLD0, PLD1, RBUF, WBUF)                          \
    {                                                                         \
        if ((KT) < 15) {                                                      \
            const short* bkt = Bf1 + (size_t)((KT) + 1) * 8192;               \
            NBH0 = *(const short8*)(bkt + ct0 * 512 + ln8);                   \
            NBH1 = *(const short8*)(bkt + ct1 * 512 + ln8);                   \
            NBL0 = *(const short8*)(bkt + 4096 + ct0 * 512 + ln8);            \
            NBL1 = *(const short8*)(bkt + 4096 + ct1 * 512 + ln8);            \
            float av[8] = {PCV0.x, PCV0.y, PCV0.z, PCV0.w,                    \
                           PCV1.x, PCV1.y, PCV1.z, PCV1.w};                   \
            short8 h8, l8;                                                    \
            _Pragma("unroll") for (int j = 0; j < 8; ++j) {                   \
                short h = bf16_rne(av[j]);                                    \
                h8[j] = h;                                                    \
                l8[j] = bf16_rne(av[j] - bf16_to_f(h));                       \
            }                                                                 \
            *(short8*)(smem + (WBUF) + aslotb) = h8;                          \
            *(short8*)(smem + (WBUF) + 4096 + aslotb) = l8;                   \
        }                                                                     \
        if ((KT) < 14) {                                                      \
            PLD0 = *(const float4*)(aptr + (size_t)((KT) + 2) * 32);          \
            PLD1 = *(const float4*)(aptr + (size_t)((KT) + 2) * 32 + 4);      \
        }                                                                     \
        {                                                                     \
            const char* Ah_c = smem + (RBUF);                                 \
            short8 Ahf[4], Alf[4];                                            \
            _Pragma("unroll") for (int rt = 0; rt < 4; ++rt) {                \
                Ahf[rt] = *(const short8*)(Ah_c + (rt * 64 + lane) * 16);     \
                Alf[rt] = *(const short8*)(Ah_c + 4096 + (rt * 64 + lane) * 16); \
            }                                                                 \
            _Pragma("unroll") for (int rt = 0; rt < 4; ++rt) {                \
                acc1[rt][0] = __builtin_amdgcn_mfma_f32_16x16x32_bf16(Ahf[rt], BH0, acc1[rt][0], 0, 0, 0); \
                acc1[rt][0] = __builtin_amdgcn_mfma_f32_16x16x32_bf16(Alf[rt], BH0, acc1[rt][0], 0, 0, 0); \
                acc1[rt][0] = __builtin_amdgcn_mfma_f32_16x16x32_bf16(Ahf[rt], BL0, acc1[rt][0], 0, 0, 0); \
                acc1[rt][1] = __builtin_amdgcn_mfma_f32_16x16x32_bf16(Ahf[rt], BH1, acc1[rt][1], 0, 0, 0); \
                acc1[rt][1] = __builtin_amdgcn_mfma_f32_16x16x32_bf16(Alf[rt], BH1, acc1[rt][1], 0, 0, 0); \
                acc1[rt][1] = __builtin_amdgcn_mfma_f32_16x16x32_bf16(Ahf[rt], BL1, acc1[rt][1], 0, 0, 0); \
            }                                                                 \
        }                                                                     \
        ldsbar();                                                             \
    }

// ---------------- fused: ef GEMM -> transpose -> g GEMM -> gates+pool ------
// Block = one (b,i) group (64 rows). 256 thr, 4 waves, 3 blocks/CU.
// LDS map (48.5 KB total):
//  phase1: A dbuf 2*8KB @0..16384 (B in registers)
//  phase2: ef_half [32][132] f32 @0 (two passes); AF 32KB @16896
//  phase3: AF only (B in registers, NO barriers)
//  epilogue: eh_s [64][132] @0 + red/s2v/ewv @33792
__global__ __launch_bounds__(256, 3) void fused_kernel(
    const float* __restrict__ x_edge,
    const short* __restrict__ Bf1, const short* __restrict__ Bf2,
    const float* __restrict__ et_b,
    const float* __restrict__ bih, const float* __restrict__ bhh,
    const float* __restrict__ natt_w, const float* __restrict__ eatt_w,
    float* __restrict__ nh_p, float* __restrict__ u_out)
{
    __shared__ __align__(16) char smem[49664];
    const int t = threadIdx.x;
    const int wv = t >> 6, lane = t & 63;
    const int g = blockIdx.x;
    const size_t bm = (size_t)g * 64;

    const int arow = t >> 2, akb = t & 3;
    const int aslotb = (((arow >> 4) * 64) + ((akb << 4) | (arow & 15))) * 16;
    const float* aptr = x_edge + (bm + arow) * 512 + akb * 8;

    const int ct0 = wv * 2, ct1 = wv * 2 + 1;
    const int ln8 = lane * 8;

    f32x4 acc1[4][2] = {};

    // phase-1 registers: A 2-deep (slotA = even kt, slotB = odd kt), B dbuf
    float4 paA0, paA1, paB0, paB1;
    short8 bhA0, bhA1, blA0, blA1, bhB0, bhB1, blB0, blB1;

    // ---- prologue: A(0),A(1) -> regs; B(0) -> regs; A(0) -> LDS buf0 ----
    paA0 = *(const float4*)(aptr);
    paA1 = *(const float4*)(aptr + 4);
    paB0 = *(const float4*)(aptr + 32);
    paB1 = *(const float4*)(aptr + 36);
    {
        const short* bkt = Bf1;
        bhA0 = *(const short8*)(bkt + ct0 * 512 + ln8);
        bhA1 = *(const short8*)(bkt + ct1 * 512 + ln8);
        blA0 = *(const short8*)(bkt + 4096 + ct0 * 512 + ln8);
        blA1 = *(const short8*)(bkt + 4096 + ct1 * 512 + ln8);
    }
    {
        float av[8] = {paA0.x, paA0.y, paA0.z, paA0.w,
                       paA1.x, paA1.y, paA1.z, paA1.w};
        short8 h8, l8;
#pragma unroll
        for (int j = 0; j < 8; ++j) {
            short h = bf16_rne(av[j]);
            h8[j] = h;
            l8[j] = bf16_rne(av[j] - bf16_to_f(h));
        }
        *(short8*)(smem + aslotb) = h8;
        *(short8*)(smem + 4096 + aslotb) = l8;
    }
    ldsbar();

    // ---- phase 1: 16 kt, lgkm-only barrier, global prefetch in flight ----
    for (int kt = 0; kt < 16; kt += 2) {
        PH1_ITER(kt, bhA0, bhA1, blA0, blA1, bhB0, bhB1, blB0, blB1,
                 paB0, paB1, paA0, paA1, 0, 8192)
        PH1_ITER(kt + 1, bhB0, bhB1, blB0, blB1, bhA0, bhA1, blA0, blA1,
                 paA0, paA1, paB0, paB1, 8192, 0)
    }

    // ---- phase 2: two 32-row half-passes: acc1+bias -> ef_half -> AF ----
    float* ef_h = (float*)smem;                 // [32][132] f32 = 16896 B
    short* AF = (short*)(smem + 16896);         // 32 KB A-fragments
#pragma unroll
    for (int h = 0; h < 2; ++h) {
        __syncthreads();    // previous contents (A dbuf / pass-0 reads) dead
#pragma unroll
        for (int c = 0; c < 2; ++c) {
            int col = wv * 32 + c * 16 + (lane & 15);
            float bias = et_b[col];
#pragma unroll
            for (int rr = 0; rr < 2; ++rr) {
                int rt = 2 * h + rr;
#pragma unroll
                for (int q = 0; q < 4; ++q) {
                    int lrow = rr * 16 + ((lane >> 4) << 2) + q;
                    ef_h[lrow * 132 + col] = acc1[rt][c][q] + bias;
                }
            }
        }
        __syncthreads();
#pragma unroll
        for (int p = 0; p < 2; ++p) {
            int unit = t + p * 256;             // 512 units: kt2(4) rr(2) ln(64)
            int kt2 = unit >> 7;
            int rr = (unit >> 6) & 1;
            int ln = unit & 63;
            int rt = 2 * h + rr;
            int lrow = rr * 16 + (ln & 15);
            int feat0 = kt2 * 32 + (ln >> 4) * 8;
            const float* src = ef_h + lrow * 132 + feat0;
            float4 v0 = *(const float4*)(src);
            float4 v1 = *(const float4*)(src + 4);
            float av[8] = {v0.x, v0.y, v0.z, v0.w, v1.x, v1.y, v1.z, v1.w};
            short8 h8, l8;
#pragma unroll
            for (int j = 0; j < 8; ++j) {
                short hh = bf16_rne(av[j]);
                h8[j] = hh;
                l8[j] = bf16_rne(av[j] - bf16_to_f(hh));
            }
            *(short8*)(AF + (((kt2 * 2 + 0) * 4 + rt) * 64 + ln) * 8) = h8;
            *(short8*)(AF + (((kt2 * 2 + 1) * 4 + rt) * 64 + ln) * 8) = l8;
        }
    }
    __syncthreads();

    // ---- phase 3: g = edge_f @ wih^T (K=128, 4 kt). B in REGISTERS, ------
    // ---- Bh-pass then Bl-pass (VGPR cap), zero barriers. -----------------
    f32x4 acc[4][6] = {};
#pragma unroll
    for (int kt = 0; kt < 4; ++kt) {
        const short* bkt = Bf2 + (size_t)kt * 24576;
        const char* Ab = (const char*)AF + kt * 8192;
        {
            short8 Bh[6];
#pragma unroll
            for (int c = 0; c < 6; ++c) {
                int ctg = ((c >> 1) << 3) + (wv << 1) + (c & 1);
                Bh[c] = *(const short8*)(bkt + ctg * 512 + ln8);
            }
#pragma unroll
            for (int rtp = 0; rtp < 2; ++rtp) {
                short8 Ah[2], Al[2];
#pragma unroll
                for (int r = 0; r < 2; ++r) {
                    Ah[r] = *(const short8*)(Ab + ((rtp * 2 + r) * 64 + lane) * 16);
                    Al[r] = *(const short8*)(Ab + 4096 + ((rtp * 2 + r) * 64 + lane) * 16);
                }
#pragma unroll
                for (int c = 0; c < 6; ++c)
#pragma unroll
                    for (int r = 0; r < 2; ++r) {
                        acc[rtp * 2 + r][c] = __builtin_amdgcn_mfma_f32_16x16x32_bf16(Ah[r], Bh[c], acc[rtp * 2 + r][c], 0, 0, 0);
                        acc[rtp * 2 + r][c] = __builtin_amdgcn_mfma_f32_16x16x32_bf16(Al[r], Bh[c], acc[rtp * 2 + r][c], 0, 0, 0);
                    }
            }
        }
        {
            short8 Bl[6];
#pragma unroll
            for (int c = 0; c < 6; ++c) {
                int ctg = ((c >> 1) << 3) + (wv << 1) + (c & 1);
                Bl[c] = *(const short8*)(bkt + 12288 + ctg * 512 + ln8);
            }
#pragma unroll
            for (int rtp = 0; rtp < 2; ++rtp) {
                short8 Ah[2];
#pragma unroll
                for (int r = 0; r < 2; ++r)
                    Ah[r] = *(const short8*)(Ab + ((rtp * 2 + r) * 64 + lane) * 16);
#pragma unroll
                for (int c = 0; c < 6; ++c)
#pragma unroll
                    for (int r = 0; r < 2; ++r)
                        acc[rtp * 2 + r][c] = __builtin_amdgcn_mfma_f32_16x16x32_bf16(Ah[r], Bl[c], acc[rtp * 2 + r][c], 0, 0, 0);
            }
        }
    }
    __syncthreads();    // AF region about to be overwritten by eh_s

    // ---- epilogue: GRU gates -> eh_s, softmax-pool (validated r3-r8) ----
    const int EHP = 132;
    float* eh_s = (float*)smem;                     // [64][132]
    float* red  = (float*)(smem + 33792);           // 256 f
    float* s2v  = red + 256;
    float* ewv  = s2v + 64;
#pragma unroll
    for (int cc = 0; cc < 2; ++cc) {
        int o = (wv << 5) + (cc << 4) + (lane & 15);
        float bco = bih[o] + bhh[o];
        float bcz = bih[128 + o] + bhh[128 + o];
        float bcn = bih[256 + o];
        float bn3 = bhh[256 + o];
#pragma unroll
        for (int rt = 0; rt < 4; ++rt) {
#pragma unroll
            for (int q = 0; q < 4; ++q) {
                int row = rt * 16 + ((lane >> 4) << 2) + q;
                float r = sigmoidf_(acc[rt][cc][q] + bco);
                float z = sigmoidf_(acc[rt][2 + cc][q] + bcz);
                float n = tanhf_(acc[rt][4 + cc][q] + bcn + r * bn3);
                eh_s[row * EHP + o] = (1.0f - z) * n;
            }
        }
    }
    __syncthreads();

    {
        int j = t >> 2, q = t & 3;
        const float* row = eh_s + j * EHP + q * 32;
        const float* wb = natt_w + 128 + q * 32;
        float a = 0.f;
#pragma unroll
        for (int k2 = 0; k2 < 32; ++k2) a = fmaf(row[k2], wb[k2], a);
        red[t] = a;
    }
    __syncthreads();
    if (t < 64) s2v[t] = red[4 * t] + red[4 * t + 1] + red[4 * t + 2] + red[4 * t + 3];
    __syncthreads();
    if (t < 64) {
        float m = -1e30f;
        for (int j = 0; j < 64; ++j) m = fmaxf(m, s2v[j]);
        ewv[t] = __expf(s2v[t] - m);
    }
    __syncthreads();
    float inv = 0.f;
    for (int j = 0; j < 64; ++j) inv += ewv[j];
    inv = 1.0f / inv;
    {
        int o = t & 127, h = t >> 7;
        float a = 0.f;
        for (int j = h * 32; j < h * 32 + 32; ++j)
            a = fmaf(ewv[j], eh_s[j * EHP + o], a);
        __syncthreads();
        red[t] = a;
    }
    __syncthreads();
    if (t < 128) {
        float v = (red[t] + red[t + 128]) * inv;
        nh_p[(size_t)g * 128 + t] = v;
        red[t] = v * eatt_w[t];
    }
    __syncthreads();
    for (int s = 64; s > 0; s >>= 1) {
        if (t < s) red[t] += red[t + s];
        __syncthreads();
    }
    if (t == 0) u_out[g] = red[0];
}

// -------- classifier input --------------------------------------------------
__global__ __launch_bounds__(128) void ci_kernel(
    const float* __restrict__ nh_p, const float* __restrict__ u,
    const int* __restrict__ pairs, float* __restrict__ ci)
{
    const int bp = blockIdx.x;
    const int b  = bp >> 7;
    const int t  = threadIdx.x;
    int i0 = pairs[bp * 2 + 0];
    int i1 = pairs[bp * 2 + 1];
    const float* n0 = nh_p + (size_t)(b * 64 + i0) * 128;
    const float* n1 = nh_p + (size_t)(b * 64 + i1) * 128;
    float s = sigmoidf_(u[b * 64 + i1] - u[b * 64 + i0]);
    float v0 = n0[t], v1 = n1[t];
    ci[(size_t)bp * 256 + t]       = 0.5f * (v0 + v1);
    ci[(size_t)bp * 256 + 128 + t] = s * v1 + (1.0f - s) * v0;
}

// -------- fused head: layer1 MFMA GEMM + ReLU + layer2 (w2 in LDS) ---------
__global__ __launch_bounds__(256, 1) void headcls_kernel(
    const float* __restrict__ ci,
    const short* __restrict__ Wf1_hi, const short* __restrict__ Wf1_lo,
    const float* __restrict__ b1a, const float* __restrict__ b1b,
    const float* __restrict__ b1c,
    const float* __restrict__ w2a, const float* __restrict__ w2b,
    const float* __restrict__ w2c,
    const float* __restrict__ b2a, const float* __restrict__ b2b,
    const float* __restrict__ b2c,
    float* __restrict__ out)
{
    __shared__ __align__(16) char smem[139264];
    const int t = threadIdx.x;
    const int wv = t >> 6, lane = t & 63;
    const int rb = blockIdx.x;
    const int hd = blockIdx.y;
    const float* b1 = hd == 0 ? b1a : hd == 1 ? b1b : b1c;
    const float* w2 = hd == 0 ? w2a : hd == 1 ? w2b : w2c;
    const float* b2 = hd == 0 ? b2a : hd == 1 ? b2b : b2c;
    const int od  = hd == 0 ? 6 : hd == 1 ? 5 : 3;
    const int off = hd == 0 ? 0 : hd == 1 ? 6 : 11;

    const int arow = t >> 2, akb = t & 3;
    const int abyte = ((((arow >> 4) * 64) + ((akb << 4) | (arow & 15))) * 8) * 2;
    const float* aptr = ci + ((size_t)rb * 32 + arow) * 256 + akb * 8;

    f32x4 acc[2][8] = {};

    float4 a0, a1;
    if (t < 128) {
        a0 = *(const float4*)(aptr);
        a1 = *(const float4*)(aptr + 4);
    }
    {
        const char* sh = (const char*)(Wf1_hi + (size_t)hd * 8 * 32 * 512);
        const char* sl = (const char*)(Wf1_lo + (size_t)hd * 8 * 32 * 512);
#pragma unroll
        for (int i = 0; i < 8; ++i) {
            int ch = i * 4 + wv;
            int o2 = ch * 1024 + lane * 16;
            gload_lds16(sh + o2, smem + ch * 1024);
            gload_lds16(sl + o2, smem + 32768 + ch * 1024);
        }
    }
    if (t < 128) {
        float av[8] = {a0.x, a0.y, a0.z, a0.w, a1.x, a1.y, a1.z, a1.w};
        short8 h8, l8;
#pragma unroll
        for (int j = 0; j < 8; ++j) {
            short h = bf16_rne(av[j]);
            h8[j] = h;
            l8[j] = bf16_rne(av[j] - bf16_to_f(h));
        }
        *(short8*)(smem + 131072 + abyte) = h8;
        *(short8*)(smem + 131072 + 2048 + abyte) = l8;
    }
    __syncthreads();

    for (int kt = 0; kt < 8; ++kt) {
        const int cur = kt & 1;
        const char* Bh_c = smem + cur * 65536;
        const char* Bl_c = Bh_c + 32768;
        const char* Ah_c = smem + 131072 + cur * 4096;
        const char* Al_c = Ah_c + 2048;

        float4 b0, b1v;
        if (kt < 7) {
            const char* sh = (const char*)(Wf1_hi + ((size_t)hd * 8 + kt + 1) * 32 * 512);
            const char* sl = (const char*)(Wf1_lo + ((size_t)hd * 8 + kt + 1) * 32 * 512);
            char* dBh = smem + (cur ^ 1) * 65536;
#pragma unroll
            for (int i = 0; i < 8; ++i) {
                int ch = i * 4 + wv;
                int o2 = ch * 1024 + lane * 16;
                gload_lds16(sh + o2, dBh + ch * 1024);
                gload_lds16(sl + o2, dBh + 32768 + ch * 1024);
            }
            if (t < 128) {
                b0  = *(const float4*)(aptr + (size_t)(kt + 1) * 32);
                b1v = *(const float4*)(aptr + (size_t)(kt + 1) * 32 + 4);
            }
        }

        short8 Ah[2], Al[2];
#pragma unroll
        for (int rt = 0; rt < 2; ++rt) {
            Ah[rt] = *(const short8*)(Ah_c + (rt * 64 + lane) * 16);
            Al[rt] = *(const short8*)(Al_c + (rt * 64 + lane) * 16);
        }
#pragma unroll
        for (int c = 0; c < 8; ++c) {
            int ctg = wv * 8 + c;
            short8 Bh = *(const short8*)(Bh_c + (ctg * 64 + lane) * 16);
            short8 Bl = *(const short8*)(Bl_c + (ctg * 64 + lane) * 16);
#pragma unroll
            for (int rt = 0; rt < 2; ++rt) {
                acc[rt][c] = __builtin_amdgcn_mfma_f32_16x16x32_bf16(Ah[rt], Bh, acc[rt][c], 0, 0, 0);
                acc[rt][c] = __builtin_amdgcn_mfma_f32_16x16x32_bf16(Al[rt], Bh, acc[rt][c], 0, 0, 0);
                acc[rt][c] = __builtin_amdgcn_mfma_f32_16x16x32_bf16(Ah[rt], Bl, acc[rt][c], 0, 0, 0);
            }
        }

        if (kt < 7 && t < 128) {
            float av[8] = {b0.x, b0.y, b0.z, b0.w, b1v.x, b1v.y, b1v.z, b1v.w};
            short8 h8, l8;
#pragma unroll
            for (int j = 0; j < 8; ++j) {
                short h = bf16_rne(av[j]);
                h8[j] = h;
                l8[j] = bf16_rne(av[j] - bf16_to_f(h));
            }
            char* dAh = smem + 131072 + (cur ^ 1) * 4096;
            *(short8*)(dAh + abyte) = h8;
            *(short8*)(dAh + 2048 + abyte) = l8;
        }
        __syncthreads();
    }

    // h_s [32][516] @0 ; w2_s @66048 (both overlay B bufs, post-sync)
    float* h_s  = (float*)smem;
    float* w2_s = (float*)(smem + 66048);
    for (int idx = t; idx < 512 * od; idx += 256) w2_s[idx] = w2[idx];
#pragma unroll
    for (int c = 0; c < 8; ++c) {
        int ctg = wv * 8 + c;
        int col = ctg * 16 + (lane & 15);
        float bias = b1[col];
#pragma unroll
        for (int rt = 0; rt < 2; ++rt) {
#pragma unroll
            for (int q = 0; q < 4; ++q) {
                int row = rt * 16 + ((lane >> 4) << 2) + q;
                h_s[row * 516 + col] = fmaxf(acc[rt][c][q] + bias, 0.f);
            }
        }
    }
    __syncthreads();

    {
        int row = t >> 3, o = t & 7;
        if (o < od) {
            const float* hr = h_s + row * 516;
            float a = b2[o];
            for (int c = 0; c < 512; ++c)
                a = fmaf(hr[c], w2_s[c * od + o], a);
            out[((size_t)rb * 32 + row) * 14 + off + o] = a;
        }
    }
}

// ---------------------------------------------------------------------------
extern "C" void kernel_launch(void* const* d_in, const int* in_sizes, int n_in,
                              void* d_out, int out_size, void* d_ws, size_t ws_size,
                              hipStream_t stream)
{
    const float* x_edge   = (const float*)d_in[1];
    const float* et_w     = (const float*)d_in[6];
    const float* et_b     = (const float*)d_in[7];
    const float* egru_wih = (const float*)d_in[11];
    const float* egru_bih = (const float*)d_in[12];
    const float* egru_bhh = (const float*)d_in[13];
    const float* natt_w   = (const float*)d_in[14];
    const float* eatt_w   = (const float*)d_in[16];
    const float* lr_w1 = (const float*)d_in[18];
    const float* lr_b1 = (const float*)d_in[19];
    const float* lr_w2 = (const float*)d_in[20];
    const float* lr_b2 = (const float*)d_in[21];
    const float* cr_w1 = (const float*)d_in[22];
    const float* cr_b1 = (const float*)d_in[23];
    const float* cr_w2 = (const float*)d_in[24];
    const float* cr_b2 = (const float*)d_in[25];
    const float* mr_w1 = (const float*)d_in[26];
    const float* mr_b1 = (const float*)d_in[27];
    const float* mr_w2 = (const float*)d_in[28];
    const float* mr_b2 = (const float*)d_in[29];
    const int* pairs   = (const int*)d_in[30];
    float* out = (float*)d_out;
    char* ws = (char*)d_ws;

    // workspace layout (bytes) — 4.66 MB total
    short* Bf1    = (short*)(ws + 0);          // 262144
    short* Bf2    = (short*)(ws + 262144);     // 196608
    short* Wf1_hi = (short*)(ws + 458752);     // 786432
    short* Wf1_lo = (short*)(ws + 1245184);    // 786432
    float* nh_p   = (float*)(ws + 2031616);    // 524288
    float* u      = (float*)(ws + 2555904);    // 4096
    float* ci     = (float*)(ws + 2560000);    // 2097152 -> end 4657152

    prep_all<<<1984, 256, 0, stream>>>(et_w, egru_wih, lr_w1, cr_w1, mr_w1,
                                       Bf1, Bf2, Wf1_hi, Wf1_lo);

    fused_kernel<<<1024, 256, 0, stream>>>(
        x_edge, Bf1, Bf2, et_b, egru_bih, egru_bhh, natt_w, eatt_w, nh_p, u);

    ci_kernel<<<2048, 128, 0, stream>>>(nh_p, u, pairs, ci);

    headcls_kernel<<<dim3(64, 3), 256, 0, stream>>>(
        ci, Wf1_hi, Wf1_lo, lr_b1, cr_b1, mr_b1,
        lr_w2, cr_w2, mr_w2, lr_b2, cr_b2, mr_b2, out);
}